// Round 8
// baseline (244.033 us; speedup 1.0000x reference)
//
#include <hip/hip_runtime.h>

#define D 20
#define ACT 5
#define NEG_SLOPE 0.2f
#define NBUK 512     // dst buckets of 256 nodes (dst >> 8)
#define CPAD 16      // counter padding: one 64-B line per bucket counter

__device__ __forceinline__ float leaky(float x) {
    return x > 0.f ? x : NEG_SLOPE * x;
}

// ---- bf16x2 packing (RNE) ----
__device__ __forceinline__ unsigned pack_bf16x2(float a, float b) {
    unsigned ua = __float_as_uint(a);
    unsigned ub = __float_as_uint(b);
    ua += 0x7fffu + ((ua >> 16) & 1u);
    ub += 0x7fffu + ((ub >> 16) & 1u);
    return (ua >> 16) | (ub & 0xffff0000u);
}
__device__ __forceinline__ float blo(unsigned u) { return __uint_as_float(u << 16); }
__device__ __forceinline__ float bhi(unsigned u) { return __uint_as_float(u & 0xffff0000u); }

// acc[d] += w * row[d]  (row = 10 bf16x2 dwords in a.xyzw, b.xyzw, c.x, c.y)
__device__ __forceinline__ void acc_row(float* acc, uint4 a, uint4 b, uint4 c, float w) {
    acc[0]  += w * blo(a.x); acc[1]  += w * bhi(a.x);
    acc[2]  += w * blo(a.y); acc[3]  += w * bhi(a.y);
    acc[4]  += w * blo(a.z); acc[5]  += w * bhi(a.z);
    acc[6]  += w * blo(a.w); acc[7]  += w * bhi(a.w);
    acc[8]  += w * blo(b.x); acc[9]  += w * bhi(b.x);
    acc[10] += w * blo(b.y); acc[11] += w * bhi(b.y);
    acc[12] += w * blo(b.z); acc[13] += w * bhi(b.z);
    acc[14] += w * blo(b.w); acc[15] += w * bhi(b.w);
    acc[16] += w * blo(c.x); acc[17] += w * bhi(c.x);
    acc[18] += w * blo(c.y); acc[19] += w * bhi(c.y);
}
// acc[d] = acc[d]*cs + w * row[d]   (online-softmax update)
__device__ __forceinline__ void fma_row(float* acc, uint4 a, uint4 b, uint4 c,
                                        float cs, float w) {
    acc[0]  = acc[0]  * cs + w * blo(a.x); acc[1]  = acc[1]  * cs + w * bhi(a.x);
    acc[2]  = acc[2]  * cs + w * blo(a.y); acc[3]  = acc[3]  * cs + w * bhi(a.y);
    acc[4]  = acc[4]  * cs + w * blo(a.z); acc[5]  = acc[5]  * cs + w * bhi(a.z);
    acc[6]  = acc[6]  * cs + w * blo(a.w); acc[7]  = acc[7]  * cs + w * bhi(a.w);
    acc[8]  = acc[8]  * cs + w * blo(b.x); acc[9]  = acc[9]  * cs + w * bhi(b.x);
    acc[10] = acc[10] * cs + w * blo(b.y); acc[11] = acc[11] * cs + w * bhi(b.y);
    acc[12] = acc[12] * cs + w * blo(b.z); acc[13] = acc[13] * cs + w * bhi(b.z);
    acc[14] = acc[14] * cs + w * blo(b.w); acc[15] = acc[15] * cs + w * bhi(b.w);
    acc[16] = acc[16] * cs + w * blo(c.x); acc[17] = acc[17] * cs + w * bhi(c.x);
    acc[18] = acc[18] * cs + w * blo(c.y); acc[19] = acc[19] * cs + w * bhi(c.y);
}

// ---------------------------------------------------------------------------
// 1. bucket histogram of dst (LDS-aggregated, int4 loads, padded counters)
// ---------------------------------------------------------------------------
__global__ void k_bhist(const int* __restrict__ dst, int* __restrict__ bkt, int e) {
    __shared__ int lh[NBUK];
    for (int b = threadIdx.x; b < NBUK; b += blockDim.x) lh[b] = 0;
    __syncthreads();
    int stride = gridDim.x * blockDim.x;
    int tid = blockIdx.x * blockDim.x + threadIdx.x;
    int n4 = e >> 2;
    const int4* d4 = (const int4*)dst;
    for (int i = tid; i < n4; i += stride) {
        int4 v = d4[i];
        atomicAdd(&lh[v.x >> 8], 1);
        atomicAdd(&lh[v.y >> 8], 1);
        atomicAdd(&lh[v.z >> 8], 1);
        atomicAdd(&lh[v.w >> 8], 1);
    }
    for (int i = (n4 << 2) + tid; i < e; i += stride)
        atomicAdd(&lh[dst[i] >> 8], 1);
    __syncthreads();
    for (int b = threadIdx.x; b < NBUK; b += blockDim.x) {
        int c = lh[b];
        if (c) atomicAdd(&bkt[b * CPAD], c);
    }
}

// ---------------------------------------------------------------------------
// 2. single-block 256-thread scan of padded bucket counts -> bbase, bcur
// ---------------------------------------------------------------------------
__global__ void k_bscan(const int* __restrict__ bkt, int* __restrict__ bbase,
                        int* __restrict__ bcur, int* __restrict__ off_n, int e) {
    __shared__ int wtot[4];
    int t = threadIdx.x;                       // 256 threads, 2 buckets each
    int c0 = bkt[(2 * t) * CPAD];
    int c1 = bkt[(2 * t + 1) * CPAD];
    int v = c0 + c1;
    int lane = t & 63, wv = t >> 6;
    int s = v;
    for (int o = 1; o < 64; o <<= 1) {
        int u = __shfl_up(s, o);
        if (lane >= o) s += u;
    }
    if (lane == 63) wtot[wv] = s;
    __syncthreads();
    int wb = 0;
    for (int k = 0; k < wv; ++k) wb += wtot[k];
    int base = wb + s - v;                     // exclusive prefix
    bbase[2 * t] = base;
    bbase[2 * t + 1] = base + c0;
    bcur[(2 * t) * CPAD] = base;
    bcur[(2 * t + 1) * CPAD] = base + c0;
    if (t == 255) bbase[NBUK] = base + v;      // == e
    if (t == 0) *off_n = e;
}

// ---------------------------------------------------------------------------
// 3. bin edges by dst bucket into tmp (packed src<<8 | dst&255), int4 loads
// ---------------------------------------------------------------------------
__global__ void k_bin(const int* __restrict__ src, const int* __restrict__ dst,
                      int* __restrict__ bcur, unsigned* __restrict__ tmp,
                      int e, int nba) {
    __shared__ int lh[NBUK];
    for (int b = threadIdx.x; b < NBUK; b += blockDim.x) lh[b] = 0;
    __syncthreads();
    int chunk = (((e + nba - 1) / nba) + 3) & ~3;     // ×4 aligned
    int lo = blockIdx.x * chunk, hi = min(lo + chunk, e);
    int cnt = hi - lo;
    int n4 = cnt > 0 ? (cnt >> 2) : 0;
    const int4* d4 = (const int4*)(dst + lo);
    for (int i = threadIdx.x; i < n4; i += blockDim.x) {
        int4 v = d4[i];
        atomicAdd(&lh[v.x >> 8], 1);
        atomicAdd(&lh[v.y >> 8], 1);
        atomicAdd(&lh[v.z >> 8], 1);
        atomicAdd(&lh[v.w >> 8], 1);
    }
    for (int j = lo + (n4 << 2) + threadIdx.x; j < hi; j += blockDim.x)
        atomicAdd(&lh[dst[j] >> 8], 1);
    __syncthreads();
    for (int b = threadIdx.x; b < NBUK; b += blockDim.x) {
        int c = lh[b];
        lh[b] = c ? atomicAdd(&bcur[b * CPAD], c) : 0;
    }
    __syncthreads();
    const int4* s4 = (const int4*)(src + lo);
    for (int i = threadIdx.x; i < n4; i += blockDim.x) {
        int4 dv = d4[i];
        int4 sv = s4[i];
        int p;
        p = atomicAdd(&lh[dv.x >> 8], 1);
        tmp[p] = ((unsigned)sv.x << 8) | (unsigned)(dv.x & 255);
        p = atomicAdd(&lh[dv.y >> 8], 1);
        tmp[p] = ((unsigned)sv.y << 8) | (unsigned)(dv.y & 255);
        p = atomicAdd(&lh[dv.z >> 8], 1);
        tmp[p] = ((unsigned)sv.z << 8) | (unsigned)(dv.z & 255);
        p = atomicAdd(&lh[dv.w >> 8], 1);
        tmp[p] = ((unsigned)sv.w << 8) | (unsigned)(dv.w & 255);
    }
    for (int j = lo + (n4 << 2) + threadIdx.x; j < hi; j += blockDim.x) {
        int t = dst[j];
        int p = atomicAdd(&lh[t >> 8], 1);
        tmp[p] = ((unsigned)src[j] << 8) | (unsigned)(t & 255);
    }
}

// ---------------------------------------------------------------------------
// 4. per-bucket: LDS node histogram + block scan -> off[]; LDS-cursor scatter
// ---------------------------------------------------------------------------
__global__ void k_scatter2(const unsigned* __restrict__ tmp, const int* __restrict__ bbase,
                           int* __restrict__ off, int* __restrict__ esrc, int n) {
    __shared__ int ldeg[256];
    __shared__ int lcur[256];
    __shared__ int wtot[4];
    int b = blockIdx.x;
    int t = threadIdx.x;
    int nlo = b << 8;
    int nloc = min(nlo + 256, n) - nlo;       // nodes in this bucket
    int lo = bbase[b], hi = bbase[b + 1];

    ldeg[t] = 0;
    __syncthreads();
    for (int i = lo + t; i < hi; i += blockDim.x)
        atomicAdd(&ldeg[tmp[i] & 255u], 1);
    __syncthreads();

    // exclusive block scan of ldeg
    int v = ldeg[t];
    int lane = t & 63, wv = t >> 6;
    int s = v;
    for (int o = 1; o < 64; o <<= 1) {
        int u = __shfl_up(s, o);
        if (lane >= o) s += u;
    }
    if (lane == 63) wtot[wv] = s;
    __syncthreads();
    int wb = 0;
    for (int k = 0; k < wv; ++k) wb += wtot[k];
    int pos = lo + wb + s - v;                // exclusive prefix + bucket base
    if (t < nloc) off[nlo + t] = pos;
    lcur[t] = pos;
    __syncthreads();

    for (int i = lo + t; i < hi; i += blockDim.x) {
        unsigned w = tmp[i];
        int p = atomicAdd(&lcur[w & 255u], 1);
        esrc[p] = (int)(w >> 8);
    }
}

// ---------------------------------------------------------------------------
// 5. h1b row i (64-B aligned): d0..d9 = bf16x2(x@gcn_W), d10 = fp32 dinv
// ---------------------------------------------------------------------------
__global__ void k_xw(const float* __restrict__ x, const float* __restrict__ W,
                     const int* __restrict__ off, uint4* __restrict__ h1b, int n) {
    __shared__ float sW[D * D];
    for (int t = threadIdx.x; t < D * D; t += blockDim.x) sW[t] = W[t];
    __syncthreads();
    int i = blockIdx.x * blockDim.x + threadIdx.x;
    if (i >= n) return;
    float xi[D];
    const float4* xr = (const float4*)(x + (size_t)i * D);
#pragma unroll
    for (int q = 0; q < D / 4; ++q) {
        float4 v = xr[q];
        xi[4 * q + 0] = v.x; xi[4 * q + 1] = v.y;
        xi[4 * q + 2] = v.z; xi[4 * q + 3] = v.w;
    }
    unsigned dw[12];
#pragma unroll
    for (int p = 0; p < 10; ++p) {
        float h0 = 0.f, h1 = 0.f;
#pragma unroll
        for (int k = 0; k < D; ++k) {
            h0 += xi[k] * sW[k * D + 2 * p];
            h1 += xi[k] * sW[k * D + 2 * p + 1];
        }
        dw[p] = pack_bf16x2(h0, h1);
    }
    int dg = off[i + 1] - off[i];
    dw[10] = __float_as_uint(rsqrtf((float)(dg + 1)));
    dw[11] = 0u;
    uint4* o = h1b + (size_t)i * 4;
    o[0] = make_uint4(dw[0], dw[1], dw[2], dw[3]);
    o[1] = make_uint4(dw[4], dw[5], dw[6], dw[7]);
    o[2] = make_uint4(dw[8], dw[9], dw[10], dw[11]);
}

// ---------------------------------------------------------------------------
// 6. fused GCN gather (4 lanes/node, bf16 rows) + relu + GAT transform
//    h2b row: d0..d9 = bf16x2 h2, d10 = fp32 a_src, d11 = fp32 a_dst
// ---------------------------------------------------------------------------
__global__ void k_gcn_gat(const int* __restrict__ off, const int* __restrict__ esrc,
                          const uint4* __restrict__ h1b, const float* __restrict__ gcn_b,
                          const float* __restrict__ gat_W, const float* __restrict__ att_s,
                          const float* __restrict__ att_d, uint4* __restrict__ h2b, int n) {
    __shared__ float sW[D * D], sb[D], sas[D], sad[D];
    for (int t = threadIdx.x; t < D * D; t += blockDim.x) sW[t] = gat_W[t];
    if (threadIdx.x < D) {
        sb[threadIdx.x]  = gcn_b[threadIdx.x];
        sas[threadIdx.x] = att_s[threadIdx.x];
        sad[threadIdx.x] = att_d[threadIdx.x];
    }
    __syncthreads();
    int t = threadIdx.x;
    int i = blockIdx.x * (blockDim.x >> 2) + (t >> 2);
    int q = t & 3;
    bool valid = i < n;

    float acc[D];
#pragma unroll
    for (int d = 0; d < D; ++d) acc[d] = 0.f;

    if (valid) {
        const uint4* row = h1b + (size_t)i * 4;
        uint4 rc = row[2];
        float di = __uint_as_float(rc.z);
        if (q == 0) {                       // self-loop term
            uint4 ra = row[0], rb = row[1];
            acc_row(acc, ra, rb, rc, di * di);
        }
        int s0 = off[i], s1 = off[i + 1];
        for (int j = s0 + q; j < s1; j += 4) {
            int s = esrc[j];
            const uint4* rs = h1b + (size_t)s * 4;
            uint4 a = rs[0], b = rs[1], c = rs[2];
            acc_row(acc, a, b, c, di * __uint_as_float(c.z));
        }
    }
    // quad all-reduce of acc
#pragma unroll
    for (int d = 0; d < D; ++d) acc[d] += __shfl_xor(acc[d], 1);
#pragma unroll
    for (int d = 0; d < D; ++d) acc[d] += __shfl_xor(acc[d], 2);

    if (valid && q == 0) {                  // lane 0: transform + pack + store
        float v[D];
#pragma unroll
        for (int k = 0; k < D; ++k) {
            float tv = acc[k] + sb[k];
            v[k] = tv > 0.f ? tv : 0.f;
        }
        unsigned dw[12];
        float as_ = 0.f, ad_ = 0.f;
#pragma unroll
        for (int p = 0; p < 10; ++p) {
            float h0 = 0.f, h1 = 0.f;
#pragma unroll
            for (int k = 0; k < D; ++k) {
                h0 += v[k] * sW[k * D + 2 * p];
                h1 += v[k] * sW[k * D + 2 * p + 1];
            }
            as_ += h0 * sas[2 * p] + h1 * sas[2 * p + 1];
            ad_ += h0 * sad[2 * p] + h1 * sad[2 * p + 1];
            dw[p] = pack_bf16x2(h0, h1);
        }
        dw[10] = __float_as_uint(as_);
        dw[11] = __float_as_uint(ad_);
        uint4* o = h2b + (size_t)i * 4;
        o[0] = make_uint4(dw[0], dw[1], dw[2], dw[3]);
        o[1] = make_uint4(dw[4], dw[5], dw[6], dw[7]);
        o[2] = make_uint4(dw[8], dw[9], dw[10], dw[11]);
    }
}

// ---------------------------------------------------------------------------
// 7. GAT online-softmax aggregate, 8 lanes/node, bf16 rows; block partial
//    -> partials[d*PB + block]
// ---------------------------------------------------------------------------
__global__ void k_gat_agg(const int* __restrict__ off, const int* __restrict__ esrc,
                          const uint4* __restrict__ h2b, const float* __restrict__ gat_b,
                          float* __restrict__ partials, int PB, int n) {
    __shared__ float sb[D];
    __shared__ float swave[4][D];
    if (threadIdx.x < D) sb[threadIdx.x] = gat_b[threadIdx.x];
    __syncthreads();
    int t = threadIdx.x;
    int i = blockIdx.x * (blockDim.x >> 3) + (t >> 3);
    int o = t & 7;
    bool valid = i < n;

    float m = -1e30f, den = 0.f;
    float acc[D];
#pragma unroll
    for (int d = 0; d < D; ++d) acc[d] = 0.f;

    if (valid) {
        const uint4* row = h2b + (size_t)i * 4;
        uint4 rc = row[2];
        float ad_i = __uint_as_float(rc.w);
        if (o == 0) {                      // self edge seeds the online softmax
            m = leaky(__uint_as_float(rc.z) + ad_i);
            den = 1.f;
            acc_row(acc, row[0], row[1], rc, 1.0f);
        }
        int s0 = off[i], s1 = off[i + 1];
        for (int j = s0 + o; j < s1; j += 8) {
            int s = esrc[j];
            const uint4* rs = h2b + (size_t)s * 4;
            uint4 a = rs[0], b = rs[1], c = rs[2];
            float eg = leaky(__uint_as_float(c.z) + ad_i);
            float nm = fmaxf(m, eg);
            float cs = __expf(m - nm), w = __expf(eg - nm);
            den = den * cs + w;
            fma_row(acc, a, b, c, cs, w);
            m = nm;
        }
    }
    // octet merge of (m, den, acc)
#pragma unroll
    for (int mask = 1; mask < 8; mask <<= 1) {
        float om = __shfl_xor(m, mask);
        float oden = __shfl_xor(den, mask);
        float nm = fmaxf(m, om);
        float c1 = __expf(m - nm), c2 = __expf(om - nm);
        den = den * c1 + oden * c2;
#pragma unroll
        for (int d = 0; d < D; ++d) {
            float oa = __shfl_xor(acc[d], mask);
            acc[d] = acc[d] * c1 + oa * c2;
        }
        m = nm;
    }
    float inv = den > 0.f ? 1.0f / den : 0.f;
#pragma unroll
    for (int d = 0; d < D; ++d) {
        float vv = acc[d] * inv + sb[d];
        vv = vv > 0.f ? vv : 0.f;
        if (!valid || o != 0) vv = 0.f;    // one contribution per node
        acc[d] = vv;
    }
    int wv = t >> 6, ln = t & 63;
#pragma unroll
    for (int d = 0; d < D; ++d) {
        float vv = acc[d];
        for (int s2 = 32; s2; s2 >>= 1) vv += __shfl_down(vv, s2);
        if (ln == 0) swave[wv][d] = vv;
    }
    __syncthreads();
    if (t < D) {
        float s = swave[0][t] + swave[1][t] + swave[2][t] + swave[3][t];
        partials[(size_t)t * PB + blockIdx.x] = s;
    }
}

// ---------------------------------------------------------------------------
// 8. final readout reduce: one block per channel, no atomics
// ---------------------------------------------------------------------------
__global__ void k_reduce(const float* __restrict__ partials, int PB, int nblk,
                         float* __restrict__ g) {
    __shared__ float swave[4];
    int d = blockIdx.x;
    int t = threadIdx.x;
    const float* p = partials + (size_t)d * PB;
    float s = 0.f;
    for (int i = t; i < nblk; i += blockDim.x) s += p[i];
    for (int s2 = 32; s2; s2 >>= 1) s += __shfl_down(s, s2);
    if ((t & 63) == 0) swave[t >> 6] = s;
    __syncthreads();
    if (t == 0) g[d] = swave[0] + swave[1] + swave[2] + swave[3];
}

// ---------------------------------------------------------------------------
// 9. dueling head
// ---------------------------------------------------------------------------
__global__ void k_head(const float* __restrict__ g,
                       const float* __restrict__ aW1, const float* __restrict__ ab1,
                       const float* __restrict__ aW2, const float* __restrict__ ab2,
                       const float* __restrict__ vW1, const float* __restrict__ vb1,
                       const float* __restrict__ vW2, const float* __restrict__ vb2,
                       float* __restrict__ out) {
    __shared__ float sg[D], t1[D], t2[D], A[ACT], V, meanA;
    int t = threadIdx.x;
    if (t < D) sg[t] = g[t];
    __syncthreads();
    if (t < D) {
        float a = ab1[t], v = vb1[t];
        for (int k = 0; k < D; ++k) {
            a += sg[k] * aW1[k * D + t];
            v += sg[k] * vW1[k * D + t];
        }
        t1[t] = a > 0.f ? a : 0.f;
        t2[t] = v > 0.f ? v : 0.f;
    }
    __syncthreads();
    if (t < ACT) {
        float a = ab2[t];
        for (int d = 0; d < D; ++d) a += t1[d] * aW2[d * ACT + t];
        A[t] = a;
    }
    if (t == D) {
        float v = vb2[0];
        for (int d = 0; d < D; ++d) v += t2[d] * vW2[d];
        V = v;
    }
    __syncthreads();
    if (t == 0) {
        float s = 0.f;
        for (int j = 0; j < ACT; ++j) s += A[j];
        meanA = s / ACT;
    }
    __syncthreads();
    if (t < ACT) out[t] = V + A[t] - meanA;
}

extern "C" void kernel_launch(void* const* d_in, const int* in_sizes, int n_in,
                              void* d_out, int out_size, void* d_ws, size_t ws_size,
                              hipStream_t stream) {
    const float* x      = (const float*)d_in[0];
    const int*   ei     = (const int*)d_in[1];
    // d_in[2] edge_attr: unused by the reference
    const float* gcn_W  = (const float*)d_in[3];
    const float* gcn_b  = (const float*)d_in[4];
    const float* gat_W  = (const float*)d_in[5];
    const float* att_s  = (const float*)d_in[6];
    const float* att_d  = (const float*)d_in[7];
    const float* gat_b  = (const float*)d_in[8];
    const float* aW1    = (const float*)d_in[9];
    const float* ab1    = (const float*)d_in[10];
    const float* aW2    = (const float*)d_in[11];
    const float* ab2    = (const float*)d_in[12];
    const float* vW1    = (const float*)d_in[13];
    const float* vb1    = (const float*)d_in[14];
    const float* vW2    = (const float*)d_in[15];
    const float* vb2    = (const float*)d_in[16];

    const int n = in_sizes[0] / D;       // 100000
    const int e = in_sizes[1] / 2;       // 3200000
    const int* src = ei;
    const int* dst = ei + e;

    const int B = 256;
    const int nb_n = (n + B - 1) / B;
    const int nb_q = (n + (B / 4) - 1) / (B / 4);   // 4 lanes/node
    const int nb_o = (n + (B / 8) - 1) / (B / 8);   // 8 lanes/node
    const int PB   = (nb_o + 63) & ~63;             // padded partials stride
    const int NBA  = 1024;                          // binning blocks (4/CU)
    const int nbuk_used = (n + 255) >> 8;           // 391

    // workspace layout
    uint4* h1b      = (uint4*)d_ws;                      // n*4 uint4 (64 B rows)
    uint4* h2b      = h1b + (size_t)n * 4;               // n*4 uint4
    float* g        = (float*)(h2b + (size_t)n * 4);     // 32 (padded)
    float* partials = g + 32;                            // D*PB
    int*   off      = (int*)(partials + (size_t)D * PB); // N+1
    int*   bkt      = off + n + 1;                       // NBUK*CPAD (padded)
    int*   bbase    = bkt + NBUK * CPAD;                 // NBUK+1
    int*   bcur     = bbase + NBUK + 1;                  // NBUK*CPAD (padded)
    int*   esrc     = bcur + NBUK * CPAD;                // E
    unsigned* tmp   = (unsigned*)d_ws;                   // E dwords; aliases h1b+h2b
                                                         // (dead before k_xw runs)

    hipMemsetAsync(bkt, 0, NBUK * CPAD * sizeof(int), stream);

    k_bhist<<<1024, B, 0, stream>>>(dst, bkt, e);
    k_bscan<<<1, 256, 0, stream>>>(bkt, bbase, bcur, &off[n], e);
    k_bin<<<NBA, B, 0, stream>>>(src, dst, bcur, tmp, e, NBA);
    k_scatter2<<<nbuk_used, B, 0, stream>>>(tmp, bbase, off, esrc, n);
    k_xw<<<nb_n, B, 0, stream>>>(x, gcn_W, off, h1b, n);
    k_gcn_gat<<<nb_q, B, 0, stream>>>(off, esrc, h1b, gcn_b, gat_W,
                                      att_s, att_d, h2b, n);
    k_gat_agg<<<nb_o, B, 0, stream>>>(off, esrc, h2b, gat_b, partials, PB, n);
    k_reduce<<<D, B, 0, stream>>>(partials, PB, nb_o, g);
    k_head<<<1, 64, 0, stream>>>(g, aW1, ab1, aW2, ab2, vW1, vb1, vW2, vb2,
                                 (float*)d_out);
}

// Round 9
// 221.735 us; speedup vs baseline: 1.1006x; 1.1006x over previous
//
#include <hip/hip_runtime.h>

#define D 20
#define ACT 5
#define NEG_SLOPE 0.2f
#define NBUK 512     // dst buckets of 256 nodes (dst >> 8)
#define CPAD 16      // counter padding: one 64-B line per bucket counter
#define NSUP 13      // super-buckets of 8192 nodes (dst >> 13); 100000>>13 = 12
#define SUBS 32      // sub-buckets per super (8192/256)

__device__ __forceinline__ float leaky(float x) {
    return x > 0.f ? x : NEG_SLOPE * x;
}

// ---- bf16x2 packing (RNE) ----
__device__ __forceinline__ unsigned pack_bf16x2(float a, float b) {
    unsigned ua = __float_as_uint(a);
    unsigned ub = __float_as_uint(b);
    ua += 0x7fffu + ((ua >> 16) & 1u);
    ub += 0x7fffu + ((ub >> 16) & 1u);
    return (ua >> 16) | (ub & 0xffff0000u);
}
__device__ __forceinline__ float blo(unsigned u) { return __uint_as_float(u << 16); }
__device__ __forceinline__ float bhi(unsigned u) { return __uint_as_float(u & 0xffff0000u); }

// acc[d] += w * row[d]  (row = 10 bf16x2 dwords in a.xyzw, b.xyzw, c.x, c.y)
__device__ __forceinline__ void acc_row(float* acc, uint4 a, uint4 b, uint4 c, float w) {
    acc[0]  += w * blo(a.x); acc[1]  += w * bhi(a.x);
    acc[2]  += w * blo(a.y); acc[3]  += w * bhi(a.y);
    acc[4]  += w * blo(a.z); acc[5]  += w * bhi(a.z);
    acc[6]  += w * blo(a.w); acc[7]  += w * bhi(a.w);
    acc[8]  += w * blo(b.x); acc[9]  += w * bhi(b.x);
    acc[10] += w * blo(b.y); acc[11] += w * bhi(b.y);
    acc[12] += w * blo(b.z); acc[13] += w * bhi(b.z);
    acc[14] += w * blo(b.w); acc[15] += w * bhi(b.w);
    acc[16] += w * blo(c.x); acc[17] += w * bhi(c.x);
    acc[18] += w * blo(c.y); acc[19] += w * bhi(c.y);
}
// acc[d] = acc[d]*cs + w * row[d]   (online-softmax update)
__device__ __forceinline__ void fma_row(float* acc, uint4 a, uint4 b, uint4 c,
                                        float cs, float w) {
    acc[0]  = acc[0]  * cs + w * blo(a.x); acc[1]  = acc[1]  * cs + w * bhi(a.x);
    acc[2]  = acc[2]  * cs + w * blo(a.y); acc[3]  = acc[3]  * cs + w * bhi(a.y);
    acc[4]  = acc[4]  * cs + w * blo(a.z); acc[5]  = acc[5]  * cs + w * bhi(a.z);
    acc[6]  = acc[6]  * cs + w * blo(a.w); acc[7]  = acc[7]  * cs + w * bhi(a.w);
    acc[8]  = acc[8]  * cs + w * blo(b.x); acc[9]  = acc[9]  * cs + w * bhi(b.x);
    acc[10] = acc[10] * cs + w * blo(b.y); acc[11] = acc[11] * cs + w * bhi(b.y);
    acc[12] = acc[12] * cs + w * blo(b.z); acc[13] = acc[13] * cs + w * bhi(b.z);
    acc[14] = acc[14] * cs + w * blo(b.w); acc[15] = acc[15] * cs + w * bhi(b.w);
    acc[16] = acc[16] * cs + w * blo(c.x); acc[17] = acc[17] * cs + w * bhi(c.x);
    acc[18] = acc[18] * cs + w * blo(c.y); acc[19] = acc[19] * cs + w * bhi(c.y);
}

// ---------------------------------------------------------------------------
// 1. bucket histogram of dst (LDS-aggregated, int4 loads, padded counters)
// ---------------------------------------------------------------------------
__global__ void k_bhist(const int* __restrict__ dst, int* __restrict__ bkt, int e) {
    __shared__ int lh[NBUK];
    for (int b = threadIdx.x; b < NBUK; b += blockDim.x) lh[b] = 0;
    __syncthreads();
    int stride = gridDim.x * blockDim.x;
    int tid = blockIdx.x * blockDim.x + threadIdx.x;
    int n4 = e >> 2;
    const int4* d4 = (const int4*)dst;
    for (int i = tid; i < n4; i += stride) {
        int4 v = d4[i];
        atomicAdd(&lh[v.x >> 8], 1);
        atomicAdd(&lh[v.y >> 8], 1);
        atomicAdd(&lh[v.z >> 8], 1);
        atomicAdd(&lh[v.w >> 8], 1);
    }
    for (int i = (n4 << 2) + tid; i < e; i += stride)
        atomicAdd(&lh[dst[i] >> 8], 1);
    __syncthreads();
    for (int b = threadIdx.x; b < NBUK; b += blockDim.x) {
        int c = lh[b];
        if (c) atomicAdd(&bkt[b * CPAD], c);
    }
}

// ---------------------------------------------------------------------------
// 2. single-block 256-thread scan of padded bucket counts -> bbase, bcur, scur
// ---------------------------------------------------------------------------
__global__ void k_bscan(const int* __restrict__ bkt, int* __restrict__ bbase,
                        int* __restrict__ bcur, int* __restrict__ scur,
                        int* __restrict__ off_n, int e) {
    __shared__ int wtot[4];
    int t = threadIdx.x;                       // 256 threads, 2 buckets each
    int c0 = bkt[(2 * t) * CPAD];
    int c1 = bkt[(2 * t + 1) * CPAD];
    int v = c0 + c1;
    int lane = t & 63, wv = t >> 6;
    int s = v;
    for (int o = 1; o < 64; o <<= 1) {
        int u = __shfl_up(s, o);
        if (lane >= o) s += u;
    }
    if (lane == 63) wtot[wv] = s;
    __syncthreads();
    int wb = 0;
    for (int k = 0; k < wv; ++k) wb += wtot[k];
    int base = wb + s - v;                     // exclusive prefix
    bbase[2 * t] = base;
    bbase[2 * t + 1] = base + c0;
    bcur[(2 * t) * CPAD] = base;
    bcur[(2 * t + 1) * CPAD] = base + c0;
    if ((t & 15) == 0) scur[(t >> 4) * CPAD] = base;  // super s=t/16 base = bbase[32s]
    if (t == 255) bbase[NBUK] = base + v;      // == e
    if (t == 0) *off_n = e;
}

// ---------------------------------------------------------------------------
// 3a. (2-pass path) Pass A: bin into NSUP supers, pack src<<13 | dst&8191
// ---------------------------------------------------------------------------
__global__ void kA_bin(const int* __restrict__ src, const int* __restrict__ dst,
                       int* __restrict__ scur, unsigned* __restrict__ tmp2,
                       int e, int nba) {
    __shared__ int lh[16];
    if (threadIdx.x < 16) lh[threadIdx.x] = 0;
    __syncthreads();
    int chunk = (((e + nba - 1) / nba) + 3) & ~3;
    int lo = blockIdx.x * chunk, hi = min(lo + chunk, e);
    int cnt = hi - lo;
    int n4 = cnt > 0 ? (cnt >> 2) : 0;
    const int4* d4 = (const int4*)(dst + lo);
    for (int i = threadIdx.x; i < n4; i += blockDim.x) {
        int4 v = d4[i];
        atomicAdd(&lh[v.x >> 13], 1);
        atomicAdd(&lh[v.y >> 13], 1);
        atomicAdd(&lh[v.z >> 13], 1);
        atomicAdd(&lh[v.w >> 13], 1);
    }
    for (int j = lo + (n4 << 2) + threadIdx.x; j < hi; j += blockDim.x)
        atomicAdd(&lh[dst[j] >> 13], 1);
    __syncthreads();
    if (threadIdx.x < 16) {
        int c = lh[threadIdx.x];
        lh[threadIdx.x] = c ? atomicAdd(&scur[threadIdx.x * CPAD], c) : 0;
    }
    __syncthreads();
    const int4* s4 = (const int4*)(src + lo);
    for (int i = threadIdx.x; i < n4; i += blockDim.x) {
        int4 dv = d4[i];
        int4 sv = s4[i];
        int p;
        p = atomicAdd(&lh[dv.x >> 13], 1);
        tmp2[p] = ((unsigned)sv.x << 13) | (unsigned)(dv.x & 8191);
        p = atomicAdd(&lh[dv.y >> 13], 1);
        tmp2[p] = ((unsigned)sv.y << 13) | (unsigned)(dv.y & 8191);
        p = atomicAdd(&lh[dv.z >> 13], 1);
        tmp2[p] = ((unsigned)sv.z << 13) | (unsigned)(dv.z & 8191);
        p = atomicAdd(&lh[dv.w >> 13], 1);
        tmp2[p] = ((unsigned)sv.w << 13) | (unsigned)(dv.w & 8191);
    }
    for (int j = lo + (n4 << 2) + threadIdx.x; j < hi; j += blockDim.x) {
        int t = dst[j];
        int p = atomicAdd(&lh[t >> 13], 1);
        tmp2[p] = ((unsigned)src[j] << 13) | (unsigned)(t & 8191);
    }
}

// ---------------------------------------------------------------------------
// 3b. (2-pass path) Pass B: per-super slice, bin into 32 sub-buckets -> tmp
// ---------------------------------------------------------------------------
__global__ void kB_bin(const unsigned* __restrict__ tmp2, const int* __restrict__ bbase,
                       int* __restrict__ bcur, unsigned* __restrict__ tmp) {
    __shared__ int lh[SUBS];
    int g = blockIdx.x;
    int s = g % NSUP;
    int slice = g / NSUP;                      // 0..31
    int b0 = s * SUBS;
    int slo = bbase[b0], shi = bbase[b0 + SUBS];
    int cnt = shi - slo;
    int sl = (cnt + 31) / 32;
    int lo = slo + slice * sl, hi = min(lo + sl, shi);
    if (threadIdx.x < SUBS) lh[threadIdx.x] = 0;
    __syncthreads();
    for (int j = lo + threadIdx.x; j < hi; j += blockDim.x)
        atomicAdd(&lh[(tmp2[j] >> 8) & 31u], 1);
    __syncthreads();
    if (threadIdx.x < SUBS) {
        int c = lh[threadIdx.x];
        lh[threadIdx.x] = c ? atomicAdd(&bcur[(b0 + threadIdx.x) * CPAD], c) : 0;
    }
    __syncthreads();
    for (int j = lo + threadIdx.x; j < hi; j += blockDim.x) {
        unsigned v = tmp2[j];
        int p = atomicAdd(&lh[(v >> 8) & 31u], 1);
        tmp[p] = ((v >> 13) << 8) | (v & 255u);
    }
}

// ---------------------------------------------------------------------------
// 3c. (fallback path, small ws) single-pass bin as in round 8
// ---------------------------------------------------------------------------
__global__ void k_bin1(const int* __restrict__ src, const int* __restrict__ dst,
                       int* __restrict__ bcur, unsigned* __restrict__ tmp,
                       int e, int nba) {
    __shared__ int lh[NBUK];
    for (int b = threadIdx.x; b < NBUK; b += blockDim.x) lh[b] = 0;
    __syncthreads();
    int chunk = (((e + nba - 1) / nba) + 3) & ~3;
    int lo = blockIdx.x * chunk, hi = min(lo + chunk, e);
    int cnt = hi - lo;
    int n4 = cnt > 0 ? (cnt >> 2) : 0;
    const int4* d4 = (const int4*)(dst + lo);
    for (int i = threadIdx.x; i < n4; i += blockDim.x) {
        int4 v = d4[i];
        atomicAdd(&lh[v.x >> 8], 1);
        atomicAdd(&lh[v.y >> 8], 1);
        atomicAdd(&lh[v.z >> 8], 1);
        atomicAdd(&lh[v.w >> 8], 1);
    }
    for (int j = lo + (n4 << 2) + threadIdx.x; j < hi; j += blockDim.x)
        atomicAdd(&lh[dst[j] >> 8], 1);
    __syncthreads();
    for (int b = threadIdx.x; b < NBUK; b += blockDim.x) {
        int c = lh[b];
        lh[b] = c ? atomicAdd(&bcur[b * CPAD], c) : 0;
    }
    __syncthreads();
    const int4* s4 = (const int4*)(src + lo);
    for (int i = threadIdx.x; i < n4; i += blockDim.x) {
        int4 dv = d4[i];
        int4 sv = s4[i];
        int p;
        p = atomicAdd(&lh[dv.x >> 8], 1);
        tmp[p] = ((unsigned)sv.x << 8) | (unsigned)(dv.x & 255);
        p = atomicAdd(&lh[dv.y >> 8], 1);
        tmp[p] = ((unsigned)sv.y << 8) | (unsigned)(dv.y & 255);
        p = atomicAdd(&lh[dv.z >> 8], 1);
        tmp[p] = ((unsigned)sv.z << 8) | (unsigned)(dv.z & 255);
        p = atomicAdd(&lh[dv.w >> 8], 1);
        tmp[p] = ((unsigned)sv.w << 8) | (unsigned)(dv.w & 255);
    }
    for (int j = lo + (n4 << 2) + threadIdx.x; j < hi; j += blockDim.x) {
        int t = dst[j];
        int p = atomicAdd(&lh[t >> 8], 1);
        tmp[p] = ((unsigned)src[j] << 8) | (unsigned)(t & 255);
    }
}

// ---------------------------------------------------------------------------
// 4. per-bucket: LDS node histogram + block scan -> off[]; LDS-cursor scatter
//    512 threads (scan by first 256)
// ---------------------------------------------------------------------------
__global__ void k_scatter2(const unsigned* __restrict__ tmp, const int* __restrict__ bbase,
                           int* __restrict__ off, int* __restrict__ esrc, int n) {
    __shared__ int ldeg[256];
    __shared__ int lcur[256];
    __shared__ int wtot[4];
    int b = blockIdx.x;
    int t = threadIdx.x;
    int nlo = b << 8;
    int nloc = min(nlo + 256, n) - nlo;       // nodes in this bucket
    int lo = bbase[b], hi = bbase[b + 1];

    if (t < 256) ldeg[t] = 0;
    __syncthreads();
    for (int i = lo + t; i < hi; i += blockDim.x)
        atomicAdd(&ldeg[tmp[i] & 255u], 1);
    __syncthreads();

    // exclusive block scan of ldeg (first 256 threads)
    if (t < 256) {
        int v = ldeg[t];
        int lane = t & 63, wv = t >> 6;
        int s = v;
        for (int o = 1; o < 64; o <<= 1) {
            int u = __shfl_up(s, o);
            if (lane >= o) s += u;
        }
        if (lane == 63) wtot[wv] = s;
        __syncthreads();
        int wb = 0;
        for (int k = 0; k < wv; ++k) wb += wtot[k];
        int pos = lo + wb + s - v;            // exclusive prefix + bucket base
        if (t < nloc) off[nlo + t] = pos;
        lcur[t] = pos;
    } else {
        __syncthreads();
    }
    __syncthreads();

    for (int i = lo + t; i < hi; i += blockDim.x) {
        unsigned w = tmp[i];
        int p = atomicAdd(&lcur[w & 255u], 1);
        esrc[p] = (int)(w >> 8);
    }
}

// ---------------------------------------------------------------------------
// 5. h1b row i (64-B aligned): d0..d9 = bf16x2(x@gcn_W), d10 = fp32 dinv
// ---------------------------------------------------------------------------
__global__ void k_xw(const float* __restrict__ x, const float* __restrict__ W,
                     const int* __restrict__ off, uint4* __restrict__ h1b, int n) {
    __shared__ float sW[D * D];
    for (int t = threadIdx.x; t < D * D; t += blockDim.x) sW[t] = W[t];
    __syncthreads();
    int i = blockIdx.x * blockDim.x + threadIdx.x;
    if (i >= n) return;
    float xi[D];
    const float4* xr = (const float4*)(x + (size_t)i * D);
#pragma unroll
    for (int q = 0; q < D / 4; ++q) {
        float4 v = xr[q];
        xi[4 * q + 0] = v.x; xi[4 * q + 1] = v.y;
        xi[4 * q + 2] = v.z; xi[4 * q + 3] = v.w;
    }
    unsigned dw[12];
#pragma unroll
    for (int p = 0; p < 10; ++p) {
        float h0 = 0.f, h1 = 0.f;
#pragma unroll
        for (int k = 0; k < D; ++k) {
            h0 += xi[k] * sW[k * D + 2 * p];
            h1 += xi[k] * sW[k * D + 2 * p + 1];
        }
        dw[p] = pack_bf16x2(h0, h1);
    }
    int dg = off[i + 1] - off[i];
    dw[10] = __float_as_uint(rsqrtf((float)(dg + 1)));
    dw[11] = 0u;
    uint4* o = h1b + (size_t)i * 4;
    o[0] = make_uint4(dw[0], dw[1], dw[2], dw[3]);
    o[1] = make_uint4(dw[4], dw[5], dw[6], dw[7]);
    o[2] = make_uint4(dw[8], dw[9], dw[10], dw[11]);
}

// ---------------------------------------------------------------------------
// 6. fused GCN gather (4 lanes/node, bf16 rows) + relu + GAT transform
// ---------------------------------------------------------------------------
__global__ void k_gcn_gat(const int* __restrict__ off, const int* __restrict__ esrc,
                          const uint4* __restrict__ h1b, const float* __restrict__ gcn_b,
                          const float* __restrict__ gat_W, const float* __restrict__ att_s,
                          const float* __restrict__ att_d, uint4* __restrict__ h2b, int n) {
    __shared__ float sW[D * D], sb[D], sas[D], sad[D];
    for (int t = threadIdx.x; t < D * D; t += blockDim.x) sW[t] = gat_W[t];
    if (threadIdx.x < D) {
        sb[threadIdx.x]  = gcn_b[threadIdx.x];
        sas[threadIdx.x] = att_s[threadIdx.x];
        sad[threadIdx.x] = att_d[threadIdx.x];
    }
    __syncthreads();
    int t = threadIdx.x;
    int i = blockIdx.x * (blockDim.x >> 2) + (t >> 2);
    int q = t & 3;
    bool valid = i < n;

    float acc[D];
#pragma unroll
    for (int d = 0; d < D; ++d) acc[d] = 0.f;

    if (valid) {
        const uint4* row = h1b + (size_t)i * 4;
        uint4 rc = row[2];
        float di = __uint_as_float(rc.z);
        if (q == 0) {                       // self-loop term
            uint4 ra = row[0], rb = row[1];
            acc_row(acc, ra, rb, rc, di * di);
        }
        int s0 = off[i], s1 = off[i + 1];
        for (int j = s0 + q; j < s1; j += 4) {
            int s = esrc[j];
            const uint4* rs = h1b + (size_t)s * 4;
            uint4 a = rs[0], b = rs[1], c = rs[2];
            acc_row(acc, a, b, c, di * __uint_as_float(c.z));
        }
    }
    // quad all-reduce of acc
#pragma unroll
    for (int d = 0; d < D; ++d) acc[d] += __shfl_xor(acc[d], 1);
#pragma unroll
    for (int d = 0; d < D; ++d) acc[d] += __shfl_xor(acc[d], 2);

    if (valid && q == 0) {                  // lane 0: transform + pack + store
        float v[D];
#pragma unroll
        for (int k = 0; k < D; ++k) {
            float tv = acc[k] + sb[k];
            v[k] = tv > 0.f ? tv : 0.f;
        }
        unsigned dw[12];
        float as_ = 0.f, ad_ = 0.f;
#pragma unroll
        for (int p = 0; p < 10; ++p) {
            float h0 = 0.f, h1 = 0.f;
#pragma unroll
            for (int k = 0; k < D; ++k) {
                h0 += v[k] * sW[k * D + 2 * p];
                h1 += v[k] * sW[k * D + 2 * p + 1];
            }
            as_ += h0 * sas[2 * p] + h1 * sas[2 * p + 1];
            ad_ += h0 * sad[2 * p] + h1 * sad[2 * p + 1];
            dw[p] = pack_bf16x2(h0, h1);
        }
        dw[10] = __float_as_uint(as_);
        dw[11] = __float_as_uint(ad_);
        uint4* o = h2b + (size_t)i * 4;
        o[0] = make_uint4(dw[0], dw[1], dw[2], dw[3]);
        o[1] = make_uint4(dw[4], dw[5], dw[6], dw[7]);
        o[2] = make_uint4(dw[8], dw[9], dw[10], dw[11]);
    }
}

// ---------------------------------------------------------------------------
// 7. GAT online-softmax aggregate, 8 lanes/node, bf16 rows
// ---------------------------------------------------------------------------
__global__ void k_gat_agg(const int* __restrict__ off, const int* __restrict__ esrc,
                          const uint4* __restrict__ h2b, const float* __restrict__ gat_b,
                          float* __restrict__ partials, int PB, int n) {
    __shared__ float sb[D];
    __shared__ float swave[4][D];
    if (threadIdx.x < D) sb[threadIdx.x] = gat_b[threadIdx.x];
    __syncthreads();
    int t = threadIdx.x;
    int i = blockIdx.x * (blockDim.x >> 3) + (t >> 3);
    int o = t & 7;
    bool valid = i < n;

    float m = -1e30f, den = 0.f;
    float acc[D];
#pragma unroll
    for (int d = 0; d < D; ++d) acc[d] = 0.f;

    if (valid) {
        const uint4* row = h2b + (size_t)i * 4;
        uint4 rc = row[2];
        float ad_i = __uint_as_float(rc.w);
        if (o == 0) {                      // self edge seeds the online softmax
            m = leaky(__uint_as_float(rc.z) + ad_i);
            den = 1.f;
            acc_row(acc, row[0], row[1], rc, 1.0f);
        }
        int s0 = off[i], s1 = off[i + 1];
        for (int j = s0 + o; j < s1; j += 8) {
            int s = esrc[j];
            const uint4* rs = h2b + (size_t)s * 4;
            uint4 a = rs[0], b = rs[1], c = rs[2];
            float eg = leaky(__uint_as_float(c.z) + ad_i);
            float nm = fmaxf(m, eg);
            float cs = __expf(m - nm), w = __expf(eg - nm);
            den = den * cs + w;
            fma_row(acc, a, b, c, cs, w);
            m = nm;
        }
    }
    // octet merge of (m, den, acc)
#pragma unroll
    for (int mask = 1; mask < 8; mask <<= 1) {
        float om = __shfl_xor(m, mask);
        float oden = __shfl_xor(den, mask);
        float nm = fmaxf(m, om);
        float c1 = __expf(m - nm), c2 = __expf(om - nm);
        den = den * c1 + oden * c2;
#pragma unroll
        for (int d = 0; d < D; ++d) {
            float oa = __shfl_xor(acc[d], mask);
            acc[d] = acc[d] * c1 + oa * c2;
        }
        m = nm;
    }
    float inv = den > 0.f ? 1.0f / den : 0.f;
#pragma unroll
    for (int d = 0; d < D; ++d) {
        float vv = acc[d] * inv + sb[d];
        vv = vv > 0.f ? vv : 0.f;
        if (!valid || o != 0) vv = 0.f;    // one contribution per node
        acc[d] = vv;
    }
    int wv = t >> 6, ln = t & 63;
#pragma unroll
    for (int d = 0; d < D; ++d) {
        float vv = acc[d];
        for (int s2 = 32; s2; s2 >>= 1) vv += __shfl_down(vv, s2);
        if (ln == 0) swave[wv][d] = vv;
    }
    __syncthreads();
    if (t < D) {
        float s = swave[0][t] + swave[1][t] + swave[2][t] + swave[3][t];
        partials[(size_t)t * PB + blockIdx.x] = s;
    }
}

// ---------------------------------------------------------------------------
// 8. final readout reduce: one block per channel, no atomics
// ---------------------------------------------------------------------------
__global__ void k_reduce(const float* __restrict__ partials, int PB, int nblk,
                         float* __restrict__ g) {
    __shared__ float swave[4];
    int d = blockIdx.x;
    int t = threadIdx.x;
    const float* p = partials + (size_t)d * PB;
    float s = 0.f;
    for (int i = t; i < nblk; i += blockDim.x) s += p[i];
    for (int s2 = 32; s2; s2 >>= 1) s += __shfl_down(s, s2);
    if ((t & 63) == 0) swave[t >> 6] = s;
    __syncthreads();
    if (t == 0) g[d] = swave[0] + swave[1] + swave[2] + swave[3];
}

// ---------------------------------------------------------------------------
// 9. dueling head
// ---------------------------------------------------------------------------
__global__ void k_head(const float* __restrict__ g,
                       const float* __restrict__ aW1, const float* __restrict__ ab1,
                       const float* __restrict__ aW2, const float* __restrict__ ab2,
                       const float* __restrict__ vW1, const float* __restrict__ vb1,
                       const float* __restrict__ vW2, const float* __restrict__ vb2,
                       float* __restrict__ out) {
    __shared__ float sg[D], t1[D], t2[D], A[ACT], V, meanA;
    int t = threadIdx.x;
    if (t < D) sg[t] = g[t];
    __syncthreads();
    if (t < D) {
        float a = ab1[t], v = vb1[t];
        for (int k = 0; k < D; ++k) {
            a += sg[k] * aW1[k * D + t];
            v += sg[k] * vW1[k * D + t];
        }
        t1[t] = a > 0.f ? a : 0.f;
        t2[t] = v > 0.f ? v : 0.f;
    }
    __syncthreads();
    if (t < ACT) {
        float a = ab2[t];
        for (int d = 0; d < D; ++d) a += t1[d] * aW2[d * ACT + t];
        A[t] = a;
    }
    if (t == D) {
        float v = vb2[0];
        for (int d = 0; d < D; ++d) v += t2[d] * vW2[d];
        V = v;
    }
    __syncthreads();
    if (t == 0) {
        float s = 0.f;
        for (int j = 0; j < ACT; ++j) s += A[j];
        meanA = s / ACT;
    }
    __syncthreads();
    if (t < ACT) out[t] = V + A[t] - meanA;
}

extern "C" void kernel_launch(void* const* d_in, const int* in_sizes, int n_in,
                              void* d_out, int out_size, void* d_ws, size_t ws_size,
                              hipStream_t stream) {
    const float* x      = (const float*)d_in[0];
    const int*   ei     = (const int*)d_in[1];
    // d_in[2] edge_attr: unused by the reference
    const float* gcn_W  = (const float*)d_in[3];
    const float* gcn_b  = (const float*)d_in[4];
    const float* gat_W  = (const float*)d_in[5];
    const float* att_s  = (const float*)d_in[6];
    const float* att_d  = (const float*)d_in[7];
    const float* gat_b  = (const float*)d_in[8];
    const float* aW1    = (const float*)d_in[9];
    const float* ab1    = (const float*)d_in[10];
    const float* aW2    = (const float*)d_in[11];
    const float* ab2    = (const float*)d_in[12];
    const float* vW1    = (const float*)d_in[13];
    const float* vb1    = (const float*)d_in[14];
    const float* vW2    = (const float*)d_in[15];
    const float* vb2    = (const float*)d_in[16];

    const int n = in_sizes[0] / D;       // 100000
    const int e = in_sizes[1] / 2;       // 3200000
    const int* src = ei;
    const int* dst = ei + e;

    const int B = 256;
    const int nb_n = (n + B - 1) / B;
    const int nb_q = (n + (B / 4) - 1) / (B / 4);   // 4 lanes/node
    const int nb_o = (n + (B / 8) - 1) / (B / 8);   // 8 lanes/node
    const int PB   = (nb_o + 63) & ~63;             // padded partials stride
    const int nbuk_used = (n + 255) >> 8;           // 391

    // workspace layout
    uint4* h1b      = (uint4*)d_ws;                      // n*4 uint4 (64 B rows)
    uint4* h2b      = h1b + (size_t)n * 4;               // n*4 uint4
    float* g        = (float*)(h2b + (size_t)n * 4);     // 32 (padded)
    float* partials = g + 32;                            // D*PB
    int*   off      = (int*)(partials + (size_t)D * PB); // N+1
    int*   bkt      = off + n + 1;                       // NBUK*CPAD
    int*   bbase    = bkt + NBUK * CPAD;                 // NBUK+1
    int*   bcur     = bbase + NBUK + 1;                  // NBUK*CPAD
    int*   scur     = bcur + NBUK * CPAD;                // 16*CPAD
    int*   esrc     = scur + 16 * CPAD;                  // E
    unsigned* tmp   = (unsigned*)(esrc + e);             // E (2-pass path)
    unsigned* tmp2  = (unsigned*)d_ws;                   // E; aliases h1b+h2b
                                                         // (dead before k_xw)

    size_t need2 = (size_t)((char*)(tmp + e) - (char*)d_ws);
    bool two_pass = ws_size >= need2;

    hipMemsetAsync(bkt, 0, NBUK * CPAD * sizeof(int), stream);

    k_bhist<<<1024, B, 0, stream>>>(dst, bkt, e);
    k_bscan<<<1, 256, 0, stream>>>(bkt, bbase, bcur, scur, &off[n], e);
    if (two_pass) {
        kA_bin<<<256, B, 0, stream>>>(src, dst, scur, tmp2, e, 256);
        kB_bin<<<NSUP * 32, B, 0, stream>>>(tmp2, bbase, bcur, tmp);
    } else {
        tmp = tmp2;   // fallback: single-pass bin, tmp aliases h1b/h2b region
        k_bin1<<<1024, B, 0, stream>>>(src, dst, bcur, tmp, e, 1024);
    }
    k_scatter2<<<nbuk_used, 512, 0, stream>>>(tmp, bbase, off, esrc, n);
    k_xw<<<nb_n, B, 0, stream>>>(x, gcn_W, off, h1b, n);
    k_gcn_gat<<<nb_q, B, 0, stream>>>(off, esrc, h1b, gcn_b, gat_W,
                                      att_s, att_d, h2b, n);
    k_gat_agg<<<nb_o, B, 0, stream>>>(off, esrc, h2b, gat_b, partials, PB, n);
    k_reduce<<<D, B, 0, stream>>>(partials, PB, nb_o, g);
    k_head<<<1, 64, 0, stream>>>(g, aW1, ab1, aW2, ab2, vW1, vb1, vW2, vb2,
                                 (float*)d_out);
}

// Round 10
// 210.886 us; speedup vs baseline: 1.1572x; 1.0514x over previous
//
#include <hip/hip_runtime.h>

#define D 20
#define ACT 5
#define NEG_SLOPE 0.2f
#define NBUK 512     // dst buckets of 256 nodes (dst >> 8)
#define CPAD 16      // counter padding: one 64-B line per bucket counter
#define NSUP 13      // super-buckets of 8192 nodes (dst >> 13)
#define SUBS 32      // sub-buckets per super (8192/256)

typedef float f32x2 __attribute__((ext_vector_type(2)));
#if defined(__has_builtin)
#if __has_builtin(__builtin_amdgcn_cvt_pk_f32_fp8) && __has_builtin(__builtin_amdgcn_cvt_pk_fp8_f32)
#define HW_FP8 1
#endif
#endif

__device__ __forceinline__ float leaky(float x) {
    return x > 0.f ? x : NEG_SLOPE * x;
}

// ---- fp8 e4m3 helpers (HW cvt when available; manual fallback, always paired) ----
#ifndef HW_FP8
__device__ __forceinline__ float dec1(unsigned b) {
    unsigned s = (b & 0x80u) << 24;
    unsigned em = (b & 0x7fu) << 20;
    return __uint_as_float(s | em) * __uint_as_float(0x7b800000u); // *2^120
}
__device__ __forceinline__ unsigned enc1(float x) {
    x = fminf(fmaxf(x, -448.f), 448.f);
    unsigned u = __float_as_uint(x * __uint_as_float(0x03800000u)); // *2^-120
    unsigned s = (u >> 24) & 0x80u;
    u &= 0x7fffffffu;
    u += 0x7ffffu + ((u >> 20) & 1u);
    unsigned v = (u >> 20) & 0x7fu;
    if (v > 0x7eu) v = 0x7eu;
    return s | v;
}
#endif

__device__ __forceinline__ void dec4(unsigned q, float* o) {
#ifdef HW_FP8
    f32x2 lo = __builtin_amdgcn_cvt_pk_f32_fp8((int)q, false);
    f32x2 hi = __builtin_amdgcn_cvt_pk_f32_fp8((int)q, true);
    o[0] = lo.x; o[1] = lo.y; o[2] = hi.x; o[3] = hi.y;
#else
    o[0] = dec1(q & 255u); o[1] = dec1((q >> 8) & 255u);
    o[2] = dec1((q >> 16) & 255u); o[3] = dec1(q >> 24);
#endif
}
__device__ __forceinline__ unsigned enc4(float a, float b, float c, float d) {
    a = fminf(fmaxf(a, -448.f), 448.f);
    b = fminf(fmaxf(b, -448.f), 448.f);
    c = fminf(fmaxf(c, -448.f), 448.f);
    d = fminf(fmaxf(d, -448.f), 448.f);
#ifdef HW_FP8
    int t = __builtin_amdgcn_cvt_pk_fp8_f32(a, b, 0, false);
    t = __builtin_amdgcn_cvt_pk_fp8_f32(c, d, t, true);
    return (unsigned)t;
#else
    return enc1(a) | (enc1(b) << 8) | (enc1(c) << 16) | (enc1(d) << 24);
#endif
}
// decode a 20-channel row (5 packed dwords) into v[20]
__device__ __forceinline__ void dec_row(uint4 a, unsigned q4, float* v) {
    dec4(a.x, v + 0); dec4(a.y, v + 4); dec4(a.z, v + 8);
    dec4(a.w, v + 12); dec4(q4, v + 16);
}

// ---------------------------------------------------------------------------
// 1. bucket histogram of dst (LDS-aggregated, int4 loads, padded counters)
// ---------------------------------------------------------------------------
__global__ void k_bhist(const int* __restrict__ dst, int* __restrict__ bkt, int e) {
    __shared__ int lh[NBUK];
    for (int b = threadIdx.x; b < NBUK; b += blockDim.x) lh[b] = 0;
    __syncthreads();
    int stride = gridDim.x * blockDim.x;
    int tid = blockIdx.x * blockDim.x + threadIdx.x;
    int n4 = e >> 2;
    const int4* d4 = (const int4*)dst;
    for (int i = tid; i < n4; i += stride) {
        int4 v = d4[i];
        atomicAdd(&lh[v.x >> 8], 1);
        atomicAdd(&lh[v.y >> 8], 1);
        atomicAdd(&lh[v.z >> 8], 1);
        atomicAdd(&lh[v.w >> 8], 1);
    }
    for (int i = (n4 << 2) + tid; i < e; i += stride)
        atomicAdd(&lh[dst[i] >> 8], 1);
    __syncthreads();
    for (int b = threadIdx.x; b < NBUK; b += blockDim.x) {
        int c = lh[b];
        if (c) atomicAdd(&bkt[b * CPAD], c);
    }
}

// ---------------------------------------------------------------------------
// 2. single-block 256-thread scan of padded bucket counts -> bbase, bcur, scur
// ---------------------------------------------------------------------------
__global__ void k_bscan(const int* __restrict__ bkt, int* __restrict__ bbase,
                        int* __restrict__ bcur, int* __restrict__ scur,
                        int* __restrict__ off_n, int e) {
    __shared__ int wtot[4];
    int t = threadIdx.x;
    int c0 = bkt[(2 * t) * CPAD];
    int c1 = bkt[(2 * t + 1) * CPAD];
    int v = c0 + c1;
    int lane = t & 63, wv = t >> 6;
    int s = v;
    for (int o = 1; o < 64; o <<= 1) {
        int u = __shfl_up(s, o);
        if (lane >= o) s += u;
    }
    if (lane == 63) wtot[wv] = s;
    __syncthreads();
    int wb = 0;
    for (int k = 0; k < wv; ++k) wb += wtot[k];
    int base = wb + s - v;
    bbase[2 * t] = base;
    bbase[2 * t + 1] = base + c0;
    bcur[(2 * t) * CPAD] = base;
    bcur[(2 * t + 1) * CPAD] = base + c0;
    if ((t & 15) == 0) scur[(t >> 4) * CPAD] = base;
    if (t == 255) bbase[NBUK] = base + v;
    if (t == 0) *off_n = e;
}

// ---------------------------------------------------------------------------
// 3a. Pass A: bin into NSUP supers, pack src<<13 | dst&8191
// ---------------------------------------------------------------------------
__global__ void kA_bin(const int* __restrict__ src, const int* __restrict__ dst,
                       int* __restrict__ scur, unsigned* __restrict__ tmp2,
                       int e, int nba) {
    __shared__ int lh[16];
    if (threadIdx.x < 16) lh[threadIdx.x] = 0;
    __syncthreads();
    int chunk = (((e + nba - 1) / nba) + 3) & ~3;
    int lo = blockIdx.x * chunk, hi = min(lo + chunk, e);
    int cnt = hi - lo;
    int n4 = cnt > 0 ? (cnt >> 2) : 0;
    const int4* d4 = (const int4*)(dst + lo);
    for (int i = threadIdx.x; i < n4; i += blockDim.x) {
        int4 v = d4[i];
        atomicAdd(&lh[v.x >> 13], 1);
        atomicAdd(&lh[v.y >> 13], 1);
        atomicAdd(&lh[v.z >> 13], 1);
        atomicAdd(&lh[v.w >> 13], 1);
    }
    for (int j = lo + (n4 << 2) + threadIdx.x; j < hi; j += blockDim.x)
        atomicAdd(&lh[dst[j] >> 13], 1);
    __syncthreads();
    if (threadIdx.x < 16) {
        int c = lh[threadIdx.x];
        lh[threadIdx.x] = c ? atomicAdd(&scur[threadIdx.x * CPAD], c) : 0;
    }
    __syncthreads();
    const int4* s4 = (const int4*)(src + lo);
    for (int i = threadIdx.x; i < n4; i += blockDim.x) {
        int4 dv = d4[i];
        int4 sv = s4[i];
        int p;
        p = atomicAdd(&lh[dv.x >> 13], 1);
        tmp2[p] = ((unsigned)sv.x << 13) | (unsigned)(dv.x & 8191);
        p = atomicAdd(&lh[dv.y >> 13], 1);
        tmp2[p] = ((unsigned)sv.y << 13) | (unsigned)(dv.y & 8191);
        p = atomicAdd(&lh[dv.z >> 13], 1);
        tmp2[p] = ((unsigned)sv.z << 13) | (unsigned)(dv.z & 8191);
        p = atomicAdd(&lh[dv.w >> 13], 1);
        tmp2[p] = ((unsigned)sv.w << 13) | (unsigned)(dv.w & 8191);
    }
    for (int j = lo + (n4 << 2) + threadIdx.x; j < hi; j += blockDim.x) {
        int t = dst[j];
        int p = atomicAdd(&lh[t >> 13], 1);
        tmp2[p] = ((unsigned)src[j] << 13) | (unsigned)(t & 8191);
    }
}

// ---------------------------------------------------------------------------
// 3b. Pass B: per-super slice, bin into 32 sub-buckets -> tmp
// ---------------------------------------------------------------------------
__global__ void kB_bin(const unsigned* __restrict__ tmp2, const int* __restrict__ bbase,
                       int* __restrict__ bcur, unsigned* __restrict__ tmp) {
    __shared__ int lh[SUBS];
    int g = blockIdx.x;
    int s = g % NSUP;
    int slice = g / NSUP;
    int b0 = s * SUBS;
    int slo = bbase[b0], shi = bbase[b0 + SUBS];
    int cnt = shi - slo;
    int sl = (cnt + 31) / 32;
    int lo = slo + slice * sl, hi = min(lo + sl, shi);
    if (threadIdx.x < SUBS) lh[threadIdx.x] = 0;
    __syncthreads();
    for (int j = lo + threadIdx.x; j < hi; j += blockDim.x)
        atomicAdd(&lh[(tmp2[j] >> 8) & 31u], 1);
    __syncthreads();
    if (threadIdx.x < SUBS) {
        int c = lh[threadIdx.x];
        lh[threadIdx.x] = c ? atomicAdd(&bcur[(b0 + threadIdx.x) * CPAD], c) : 0;
    }
    __syncthreads();
    for (int j = lo + threadIdx.x; j < hi; j += blockDim.x) {
        unsigned v = tmp2[j];
        int p = atomicAdd(&lh[(v >> 8) & 31u], 1);
        tmp[p] = ((v >> 13) << 8) | (v & 255u);
    }
}

// ---------------------------------------------------------------------------
// 3c. fallback (small ws): single-pass bin
// ---------------------------------------------------------------------------
__global__ void k_bin1(const int* __restrict__ src, const int* __restrict__ dst,
                       int* __restrict__ bcur, unsigned* __restrict__ tmp,
                       int e, int nba) {
    __shared__ int lh[NBUK];
    for (int b = threadIdx.x; b < NBUK; b += blockDim.x) lh[b] = 0;
    __syncthreads();
    int chunk = (((e + nba - 1) / nba) + 3) & ~3;
    int lo = blockIdx.x * chunk, hi = min(lo + chunk, e);
    for (int j = lo + threadIdx.x; j < hi; j += blockDim.x)
        atomicAdd(&lh[dst[j] >> 8], 1);
    __syncthreads();
    for (int b = threadIdx.x; b < NBUK; b += blockDim.x) {
        int c = lh[b];
        lh[b] = c ? atomicAdd(&bcur[b * CPAD], c) : 0;
    }
    __syncthreads();
    for (int j = lo + threadIdx.x; j < hi; j += blockDim.x) {
        int t = dst[j];
        int p = atomicAdd(&lh[t >> 8], 1);
        tmp[p] = ((unsigned)src[j] << 8) | (unsigned)(t & 255);
    }
}

// ---------------------------------------------------------------------------
// 4. per-bucket: LDS node histogram + block scan -> off[]; LDS-cursor scatter
// ---------------------------------------------------------------------------
__global__ void k_scatter2(const unsigned* __restrict__ tmp, const int* __restrict__ bbase,
                           int* __restrict__ off, int* __restrict__ esrc, int n) {
    __shared__ int ldeg[256];
    __shared__ int lcur[256];
    __shared__ int wtot[4];
    int b = blockIdx.x;
    int t = threadIdx.x;
    int nlo = b << 8;
    int nloc = min(nlo + 256, n) - nlo;
    int lo = bbase[b], hi = bbase[b + 1];

    if (t < 256) ldeg[t] = 0;
    __syncthreads();
    for (int i = lo + t; i < hi; i += blockDim.x)
        atomicAdd(&ldeg[tmp[i] & 255u], 1);
    __syncthreads();

    if (t < 256) {
        int v = ldeg[t];
        int lane = t & 63, wv = t >> 6;
        int s = v;
        for (int o = 1; o < 64; o <<= 1) {
            int u = __shfl_up(s, o);
            if (lane >= o) s += u;
        }
        if (lane == 63) wtot[wv] = s;
        __syncthreads();
        int wb = 0;
        for (int k = 0; k < wv; ++k) wb += wtot[k];
        int pos = lo + wb + s - v;
        if (t < nloc) off[nlo + t] = pos;
        lcur[t] = pos;
    } else {
        __syncthreads();
    }
    __syncthreads();

    for (int i = lo + t; i < hi; i += blockDim.x) {
        unsigned w = tmp[i];
        int p = atomicAdd(&lcur[w & 255u], 1);
        esrc[p] = (int)(w >> 8);
    }
}

// ---------------------------------------------------------------------------
// 5. h1c row i (32-B): dw0..4 = 20 fp8(x@gcn_W), dw5 = fp32 dinv, pad
// ---------------------------------------------------------------------------
__global__ void k_xw(const float* __restrict__ x, const float* __restrict__ W,
                     const int* __restrict__ off, uint4* __restrict__ h1c, int n) {
    __shared__ float sW[D * D];
    for (int t = threadIdx.x; t < D * D; t += blockDim.x) sW[t] = W[t];
    __syncthreads();
    int i = blockIdx.x * blockDim.x + threadIdx.x;
    if (i >= n) return;
    float xi[D];
    const float4* xr = (const float4*)(x + (size_t)i * D);
#pragma unroll
    for (int q = 0; q < D / 4; ++q) {
        float4 v = xr[q];
        xi[4 * q + 0] = v.x; xi[4 * q + 1] = v.y;
        xi[4 * q + 2] = v.z; xi[4 * q + 3] = v.w;
    }
    float h[D];
#pragma unroll
    for (int d = 0; d < D; ++d) {
        float a = 0.f;
#pragma unroll
        for (int k = 0; k < D; ++k) a += xi[k] * sW[k * D + d];
        h[d] = a;
    }
    int dg = off[i + 1] - off[i];
    uint4* o = h1c + (size_t)i * 2;
    o[0] = make_uint4(enc4(h[0], h[1], h[2], h[3]), enc4(h[4], h[5], h[6], h[7]),
                      enc4(h[8], h[9], h[10], h[11]), enc4(h[12], h[13], h[14], h[15]));
    o[1] = make_uint4(enc4(h[16], h[17], h[18], h[19]),
                      __float_as_uint(rsqrtf((float)(dg + 1))), 0u, 0u);
}

// ---------------------------------------------------------------------------
// 6. fused GCN gather (8 lanes/node, fp8 rows) + relu + GAT transform
//    h2c row: dw0..4 = fp8 h2, dw5 = fp32 a_src, dw6 = fp32 a_dst, pad
// ---------------------------------------------------------------------------
__global__ void k_gcn_gat(const int* __restrict__ off, const int* __restrict__ esrc,
                          const uint4* __restrict__ h1c, const float* __restrict__ gcn_b,
                          const float* __restrict__ gat_W, const float* __restrict__ att_s,
                          const float* __restrict__ att_d, uint4* __restrict__ h2c, int n) {
    __shared__ float sW[D * D], sb[D], sas[D], sad[D];
    for (int t = threadIdx.x; t < D * D; t += blockDim.x) sW[t] = gat_W[t];
    if (threadIdx.x < D) {
        sb[threadIdx.x]  = gcn_b[threadIdx.x];
        sas[threadIdx.x] = att_s[threadIdx.x];
        sad[threadIdx.x] = att_d[threadIdx.x];
    }
    __syncthreads();
    int t = threadIdx.x;
    int i = blockIdx.x * (blockDim.x >> 3) + (t >> 3);
    int q = t & 7;
    bool valid = i < n;

    float acc[D];
#pragma unroll
    for (int d = 0; d < D; ++d) acc[d] = 0.f;

    if (valid) {
        const uint4* row = h1c + (size_t)i * 2;
        uint4 r1 = row[1];
        float di = __uint_as_float(r1.y);
        if (q == 0) {                       // self-loop term
            float v[D];
            dec_row(row[0], r1.x, v);
            float c = di * di;
#pragma unroll
            for (int d = 0; d < D; ++d) acc[d] = c * v[d];
        }
        int s0 = off[i], s1 = off[i + 1];
        for (int j = s0 + q; j < s1; j += 8) {
            int s = esrc[j];
            const uint4* rs = h1c + (size_t)s * 2;
            uint4 a = rs[0];
            uint2 b = *(const uint2*)(rs + 1);
            float v[D];
            dec_row(a, b.x, v);
            float norm = di * __uint_as_float(b.y);
#pragma unroll
            for (int d = 0; d < D; ++d) acc[d] += norm * v[d];
        }
    }
    // octet all-reduce of acc
#pragma unroll
    for (int d = 0; d < D; ++d) acc[d] += __shfl_xor(acc[d], 1);
#pragma unroll
    for (int d = 0; d < D; ++d) acc[d] += __shfl_xor(acc[d], 2);
#pragma unroll
    for (int d = 0; d < D; ++d) acc[d] += __shfl_xor(acc[d], 4);

    if (valid && q == 0) {                  // lane 0: transform + pack + store
        float v[D];
#pragma unroll
        for (int k = 0; k < D; ++k) {
            float tv = acc[k] + sb[k];
            v[k] = tv > 0.f ? tv : 0.f;
        }
        float h[D];
        float as_ = 0.f, ad_ = 0.f;
#pragma unroll
        for (int d = 0; d < D; ++d) {
            float a = 0.f;
#pragma unroll
            for (int k = 0; k < D; ++k) a += v[k] * sW[k * D + d];
            h[d] = a;
            as_ += a * sas[d];
            ad_ += a * sad[d];
        }
        uint4* o = h2c + (size_t)i * 2;
        o[0] = make_uint4(enc4(h[0], h[1], h[2], h[3]), enc4(h[4], h[5], h[6], h[7]),
                          enc4(h[8], h[9], h[10], h[11]), enc4(h[12], h[13], h[14], h[15]));
        o[1] = make_uint4(enc4(h[16], h[17], h[18], h[19]),
                          __float_as_uint(as_), __float_as_uint(ad_), 0u);
    }
}

// ---------------------------------------------------------------------------
// 7. GAT online-softmax aggregate, 8 lanes/node, fp8 rows; block partials
// ---------------------------------------------------------------------------
__global__ void k_gat_agg(const int* __restrict__ off, const int* __restrict__ esrc,
                          const uint4* __restrict__ h2c, const float* __restrict__ gat_b,
                          float* __restrict__ partials, int PB, int n) {
    __shared__ float sb[D];
    __shared__ float swave[4][D];
    if (threadIdx.x < D) sb[threadIdx.x] = gat_b[threadIdx.x];
    __syncthreads();
    int t = threadIdx.x;
    int i = blockIdx.x * (blockDim.x >> 3) + (t >> 3);
    int o = t & 7;
    bool valid = i < n;

    float m = -1e30f, den = 0.f;
    float acc[D];
#pragma unroll
    for (int d = 0; d < D; ++d) acc[d] = 0.f;

    float ad_i = 0.f;
    if (valid) {
        const uint4* row = h2c + (size_t)i * 2;
        uint4 r1 = row[1];
        ad_i = __uint_as_float(r1.z);
        if (o == 0) {                      // self edge seeds the online softmax
            m = leaky(__uint_as_float(r1.y) + ad_i);
            den = 1.f;
            float v[D];
            dec_row(row[0], r1.x, v);
#pragma unroll
            for (int d = 0; d < D; ++d) acc[d] = v[d];
        }
        int s0 = off[i], s1 = off[i + 1];
        for (int j = s0 + o; j < s1; j += 8) {
            int s = esrc[j];
            const uint4* rs = h2c + (size_t)s * 2;
            uint4 a = rs[0];
            uint4 b = rs[1];
            float v[D];
            dec_row(a, b.x, v);
            float eg = leaky(__uint_as_float(b.y) + ad_i);
            float nm = fmaxf(m, eg);
            float cs = __expf(m - nm), w = __expf(eg - nm);
            den = den * cs + w;
#pragma unroll
            for (int d = 0; d < D; ++d) acc[d] = acc[d] * cs + w * v[d];
            m = nm;
        }
    }
    // octet merge of (m, den, acc)
#pragma unroll
    for (int mask = 1; mask < 8; mask <<= 1) {
        float om = __shfl_xor(m, mask);
        float oden = __shfl_xor(den, mask);
        float nm = fmaxf(m, om);
        float c1 = __expf(m - nm), c2 = __expf(om - nm);
        den = den * c1 + oden * c2;
#pragma unroll
        for (int d = 0; d < D; ++d) {
            float oa = __shfl_xor(acc[d], mask);
            acc[d] = acc[d] * c1 + oa * c2;
        }
        m = nm;
    }
    float inv = den > 0.f ? 1.0f / den : 0.f;
#pragma unroll
    for (int d = 0; d < D; ++d) {
        float vv = acc[d] * inv + sb[d];
        vv = vv > 0.f ? vv : 0.f;
        if (!valid || o != 0) vv = 0.f;
        acc[d] = vv;
    }
    int wv = t >> 6, ln = t & 63;
#pragma unroll
    for (int d = 0; d < D; ++d) {
        float vv = acc[d];
        for (int s2 = 32; s2; s2 >>= 1) vv += __shfl_down(vv, s2);
        if (ln == 0) swave[wv][d] = vv;
    }
    __syncthreads();
    if (t < D) {
        float s = swave[0][t] + swave[1][t] + swave[2][t] + swave[3][t];
        partials[(size_t)t * PB + blockIdx.x] = s;
    }
}

// ---------------------------------------------------------------------------
// 8. final readout reduce: one block per channel, no atomics
// ---------------------------------------------------------------------------
__global__ void k_reduce(const float* __restrict__ partials, int PB, int nblk,
                         float* __restrict__ g) {
    __shared__ float swave[4];
    int d = blockIdx.x;
    int t = threadIdx.x;
    const float* p = partials + (size_t)d * PB;
    float s = 0.f;
    for (int i = t; i < nblk; i += blockDim.x) s += p[i];
    for (int s2 = 32; s2; s2 >>= 1) s += __shfl_down(s, s2);
    if ((t & 63) == 0) swave[t >> 6] = s;
    __syncthreads();
    if (t == 0) g[d] = swave[0] + swave[1] + swave[2] + swave[3];
}

// ---------------------------------------------------------------------------
// 9. dueling head
// ---------------------------------------------------------------------------
__global__ void k_head(const float* __restrict__ g,
                       const float* __restrict__ aW1, const float* __restrict__ ab1,
                       const float* __restrict__ aW2, const float* __restrict__ ab2,
                       const float* __restrict__ vW1, const float* __restrict__ vb1,
                       const float* __restrict__ vW2, const float* __restrict__ vb2,
                       float* __restrict__ out) {
    __shared__ float sg[D], t1[D], t2[D], A[ACT], V, meanA;
    int t = threadIdx.x;
    if (t < D) sg[t] = g[t];
    __syncthreads();
    if (t < D) {
        float a = ab1[t], v = vb1[t];
        for (int k = 0; k < D; ++k) {
            a += sg[k] * aW1[k * D + t];
            v += sg[k] * vW1[k * D + t];
        }
        t1[t] = a > 0.f ? a : 0.f;
        t2[t] = v > 0.f ? v : 0.f;
    }
    __syncthreads();
    if (t < ACT) {
        float a = ab2[t];
        for (int d = 0; d < D; ++d) a += t1[d] * aW2[d * ACT + t];
        A[t] = a;
    }
    if (t == D) {
        float v = vb2[0];
        for (int d = 0; d < D; ++d) v += t2[d] * vW2[d];
        V = v;
    }
    __syncthreads();
    if (t == 0) {
        float s = 0.f;
        for (int j = 0; j < ACT; ++j) s += A[j];
        meanA = s / ACT;
    }
    __syncthreads();
    if (t < ACT) out[t] = V + A[t] - meanA;
}

extern "C" void kernel_launch(void* const* d_in, const int* in_sizes, int n_in,
                              void* d_out, int out_size, void* d_ws, size_t ws_size,
                              hipStream_t stream) {
    const float* x      = (const float*)d_in[0];
    const int*   ei     = (const int*)d_in[1];
    // d_in[2] edge_attr: unused by the reference
    const float* gcn_W  = (const float*)d_in[3];
    const float* gcn_b  = (const float*)d_in[4];
    const float* gat_W  = (const float*)d_in[5];
    const float* att_s  = (const float*)d_in[6];
    const float* att_d  = (const float*)d_in[7];
    const float* gat_b  = (const float*)d_in[8];
    const float* aW1    = (const float*)d_in[9];
    const float* ab1    = (const float*)d_in[10];
    const float* aW2    = (const float*)d_in[11];
    const float* ab2    = (const float*)d_in[12];
    const float* vW1    = (const float*)d_in[13];
    const float* vb1    = (const float*)d_in[14];
    const float* vW2    = (const float*)d_in[15];
    const float* vb2    = (const float*)d_in[16];

    const int n = in_sizes[0] / D;       // 100000
    const int e = in_sizes[1] / 2;       // 3200000
    const int* src = ei;
    const int* dst = ei + e;

    const int B = 256;
    const int nb_n = (n + B - 1) / B;
    const int nb_o = (n + 31) / 32;                 // 8 lanes/node
    const int PB   = (nb_o + 63) & ~63;
    const int nbuk_used = (n + 255) >> 8;           // 391

    // workspace layout: region A = max(E dwords, h1c+h2c) — tmp2 dead before k_xw
    char* p = (char*)d_ws;
    size_t regionA = (size_t)e * 4;
    size_t hsz = (size_t)n * 64;                    // h1c(32B) + h2c(32B) per node
    if (hsz > regionA) regionA = hsz;
    uint4* h1c      = (uint4*)p;                    // n*2 uint4
    uint4* h2c      = h1c + (size_t)n * 2;          // n*2 uint4
    unsigned* tmp2  = (unsigned*)p;                 // E dwords (aliases h1c/h2c)
    p += regionA;
    float* g        = (float*)p;        p += 32 * sizeof(float);
    float* partials = (float*)p;        p += (size_t)D * PB * sizeof(float);
    int*   off      = (int*)p;          p += (size_t)(n + 1) * sizeof(int);
    int*   bkt      = (int*)p;          p += (size_t)NBUK * CPAD * sizeof(int);
    int*   bbase    = (int*)p;          p += (size_t)(NBUK + 1) * sizeof(int);
    int*   bcur     = (int*)p;          p += (size_t)NBUK * CPAD * sizeof(int);
    int*   scur     = (int*)p;          p += (size_t)16 * CPAD * sizeof(int);
    int*   esrc     = (int*)p;          p += (size_t)e * sizeof(int);
    unsigned* tmp   = (unsigned*)p;     p += (size_t)e * sizeof(unsigned);
    size_t need2 = (size_t)(p - (char*)d_ws);
    bool two_pass = ws_size >= need2;

    hipMemsetAsync(bkt, 0, NBUK * CPAD * sizeof(int), stream);

    k_bhist<<<1024, B, 0, stream>>>(dst, bkt, e);
    k_bscan<<<1, 256, 0, stream>>>(bkt, bbase, bcur, scur, &off[n], e);
    if (two_pass) {
        kA_bin<<<256, B, 0, stream>>>(src, dst, scur, tmp2, e, 256);
        kB_bin<<<NSUP * 32, B, 0, stream>>>(tmp2, bbase, bcur, tmp);
    } else {
        tmp = tmp2;   // fallback: single-pass bin into region A
        k_bin1<<<1024, B, 0, stream>>>(src, dst, bcur, tmp, e, 1024);
    }
    k_scatter2<<<nbuk_used, 512, 0, stream>>>(tmp, bbase, off, esrc, n);
    k_xw<<<nb_n, B, 0, stream>>>(x, gcn_W, off, h1c, n);
    k_gcn_gat<<<nb_o, B, 0, stream>>>(off, esrc, h1c, gcn_b, gat_W,
                                      att_s, att_d, h2c, n);
    k_gat_agg<<<nb_o, B, 0, stream>>>(off, esrc, h2c, gat_b, partials, PB, n);
    k_reduce<<<D, B, 0, stream>>>(partials, PB, nb_o, g);
    k_head<<<1, 64, 0, stream>>>(g, aW1, ab1, aW2, ab2, vW1, vb1, vW2, vb2,
                                 (float*)d_out);
}

// Round 11
// 194.795 us; speedup vs baseline: 1.2528x; 1.0826x over previous
//
#include <hip/hip_runtime.h>

#define D 20
#define ACT 5
#define NEG_SLOPE 0.2f
#define NBUK 512     // dst buckets of 256 nodes (dst >> 8)
#define CPAD 16      // counter padding: one 64-B line per bucket counter
#define NSUP 13      // super-buckets of 8192 nodes (dst >> 13)
#define SUBS 32      // sub-buckets per super (8192/256)

typedef float f32x2 __attribute__((ext_vector_type(2)));
#if defined(__has_builtin)
#if __has_builtin(__builtin_amdgcn_cvt_pk_f32_fp8) && __has_builtin(__builtin_amdgcn_cvt_pk_fp8_f32)
#define HW_FP8 1
#endif
#endif

__device__ __forceinline__ float leaky(float x) {
    return x > 0.f ? x : NEG_SLOPE * x;
}

// ---- fp8 e4m3 helpers (HW cvt when available; manual fallback, always paired) ----
#ifndef HW_FP8
__device__ __forceinline__ float dec1(unsigned b) {
    unsigned s = (b & 0x80u) << 24;
    unsigned em = (b & 0x7fu) << 20;
    return __uint_as_float(s | em) * __uint_as_float(0x7b800000u); // *2^120
}
__device__ __forceinline__ unsigned enc1(float x) {
    x = fminf(fmaxf(x, -448.f), 448.f);
    unsigned u = __float_as_uint(x * __uint_as_float(0x03800000u)); // *2^-120
    unsigned s = (u >> 24) & 0x80u;
    u &= 0x7fffffffu;
    u += 0x7ffffu + ((u >> 20) & 1u);
    unsigned v = (u >> 20) & 0x7fu;
    if (v > 0x7eu) v = 0x7eu;
    return s | v;
}
#endif

__device__ __forceinline__ void dec4(unsigned q, float* o) {
#ifdef HW_FP8
    f32x2 lo = __builtin_amdgcn_cvt_pk_f32_fp8((int)q, false);
    f32x2 hi = __builtin_amdgcn_cvt_pk_f32_fp8((int)q, true);
    o[0] = lo.x; o[1] = lo.y; o[2] = hi.x; o[3] = hi.y;
#else
    o[0] = dec1(q & 255u); o[1] = dec1((q >> 8) & 255u);
    o[2] = dec1((q >> 16) & 255u); o[3] = dec1(q >> 24);
#endif
}
__device__ __forceinline__ unsigned enc4(float a, float b, float c, float d) {
    a = fminf(fmaxf(a, -448.f), 448.f);
    b = fminf(fmaxf(b, -448.f), 448.f);
    c = fminf(fmaxf(c, -448.f), 448.f);
    d = fminf(fmaxf(d, -448.f), 448.f);
#ifdef HW_FP8
    int t = __builtin_amdgcn_cvt_pk_fp8_f32(a, b, 0, false);
    t = __builtin_amdgcn_cvt_pk_fp8_f32(c, d, t, true);
    return (unsigned)t;
#else
    return enc1(a) | (enc1(b) << 8) | (enc1(c) << 16) | (enc1(d) << 24);
#endif
}
// decode a 20-channel row (5 packed dwords) into v[20]
__device__ __forceinline__ void dec_row(uint4 a, unsigned q4, float* v) {
    dec4(a.x, v + 0); dec4(a.y, v + 4); dec4(a.z, v + 8);
    dec4(a.w, v + 12); dec4(q4, v + 16);
}

// ---------------------------------------------------------------------------
// 1. bucket histogram of dst (LDS-aggregated, int4 loads, padded counters)
// ---------------------------------------------------------------------------
__global__ void k_bhist(const int* __restrict__ dst, int* __restrict__ bkt, int e) {
    __shared__ int lh[NBUK];
    for (int b = threadIdx.x; b < NBUK; b += blockDim.x) lh[b] = 0;
    __syncthreads();
    int stride = gridDim.x * blockDim.x;
    int tid = blockIdx.x * blockDim.x + threadIdx.x;
    int n4 = e >> 2;
    const int4* d4 = (const int4*)dst;
    for (int i = tid; i < n4; i += stride) {
        int4 v = d4[i];
        atomicAdd(&lh[v.x >> 8], 1);
        atomicAdd(&lh[v.y >> 8], 1);
        atomicAdd(&lh[v.z >> 8], 1);
        atomicAdd(&lh[v.w >> 8], 1);
    }
    for (int i = (n4 << 2) + tid; i < e; i += stride)
        atomicAdd(&lh[dst[i] >> 8], 1);
    __syncthreads();
    for (int b = threadIdx.x; b < NBUK; b += blockDim.x) {
        int c = lh[b];
        if (c) atomicAdd(&bkt[b * CPAD], c);
    }
}

// ---------------------------------------------------------------------------
// 2. single-block 256-thread scan of padded bucket counts -> bbase, bcur, scur
// ---------------------------------------------------------------------------
__global__ void k_bscan(const int* __restrict__ bkt, int* __restrict__ bbase,
                        int* __restrict__ bcur, int* __restrict__ scur,
                        int* __restrict__ off_n, int e) {
    __shared__ int wtot[4];
    int t = threadIdx.x;
    int c0 = bkt[(2 * t) * CPAD];
    int c1 = bkt[(2 * t + 1) * CPAD];
    int v = c0 + c1;
    int lane = t & 63, wv = t >> 6;
    int s = v;
    for (int o = 1; o < 64; o <<= 1) {
        int u = __shfl_up(s, o);
        if (lane >= o) s += u;
    }
    if (lane == 63) wtot[wv] = s;
    __syncthreads();
    int wb = 0;
    for (int k = 0; k < wv; ++k) wb += wtot[k];
    int base = wb + s - v;
    bbase[2 * t] = base;
    bbase[2 * t + 1] = base + c0;
    bcur[(2 * t) * CPAD] = base;
    bcur[(2 * t + 1) * CPAD] = base + c0;
    if ((t & 15) == 0) scur[(t >> 4) * CPAD] = base;
    if (t == 255) bbase[NBUK] = base + v;
    if (t == 0) *off_n = e;
}

// ---------------------------------------------------------------------------
// 3a. Pass A: bin into NSUP supers, pack src<<13 | dst&8191
// ---------------------------------------------------------------------------
__global__ void kA_bin(const int* __restrict__ src, const int* __restrict__ dst,
                       int* __restrict__ scur, unsigned* __restrict__ tmp2,
                       int e, int nba) {
    __shared__ int lh[16];
    if (threadIdx.x < 16) lh[threadIdx.x] = 0;
    __syncthreads();
    int chunk = (((e + nba - 1) / nba) + 3) & ~3;
    int lo = blockIdx.x * chunk, hi = min(lo + chunk, e);
    int cnt = hi - lo;
    int n4 = cnt > 0 ? (cnt >> 2) : 0;
    const int4* d4 = (const int4*)(dst + lo);
    for (int i = threadIdx.x; i < n4; i += blockDim.x) {
        int4 v = d4[i];
        atomicAdd(&lh[v.x >> 13], 1);
        atomicAdd(&lh[v.y >> 13], 1);
        atomicAdd(&lh[v.z >> 13], 1);
        atomicAdd(&lh[v.w >> 13], 1);
    }
    for (int j = lo + (n4 << 2) + threadIdx.x; j < hi; j += blockDim.x)
        atomicAdd(&lh[dst[j] >> 13], 1);
    __syncthreads();
    if (threadIdx.x < 16) {
        int c = lh[threadIdx.x];
        lh[threadIdx.x] = c ? atomicAdd(&scur[threadIdx.x * CPAD], c) : 0;
    }
    __syncthreads();
    const int4* s4 = (const int4*)(src + lo);
    for (int i = threadIdx.x; i < n4; i += blockDim.x) {
        int4 dv = d4[i];
        int4 sv = s4[i];
        int p;
        p = atomicAdd(&lh[dv.x >> 13], 1);
        tmp2[p] = ((unsigned)sv.x << 13) | (unsigned)(dv.x & 8191);
        p = atomicAdd(&lh[dv.y >> 13], 1);
        tmp2[p] = ((unsigned)sv.y << 13) | (unsigned)(dv.y & 8191);
        p = atomicAdd(&lh[dv.z >> 13], 1);
        tmp2[p] = ((unsigned)sv.z << 13) | (unsigned)(dv.z & 8191);
        p = atomicAdd(&lh[dv.w >> 13], 1);
        tmp2[p] = ((unsigned)sv.w << 13) | (unsigned)(dv.w & 8191);
    }
    for (int j = lo + (n4 << 2) + threadIdx.x; j < hi; j += blockDim.x) {
        int t = dst[j];
        int p = atomicAdd(&lh[t >> 13], 1);
        tmp2[p] = ((unsigned)src[j] << 13) | (unsigned)(t & 8191);
    }
}

// ---------------------------------------------------------------------------
// 3b. Pass B: per-super slice, bin into 32 sub-buckets -> tmp
// ---------------------------------------------------------------------------
__global__ void kB_bin(const unsigned* __restrict__ tmp2, const int* __restrict__ bbase,
                       int* __restrict__ bcur, unsigned* __restrict__ tmp) {
    __shared__ int lh[SUBS];
    int g = blockIdx.x;
    int s = g % NSUP;
    int slice = g / NSUP;
    int b0 = s * SUBS;
    int slo = bbase[b0], shi = bbase[b0 + SUBS];
    int cnt = shi - slo;
    int sl = (cnt + 31) / 32;
    int lo = slo + slice * sl, hi = min(lo + sl, shi);
    if (threadIdx.x < SUBS) lh[threadIdx.x] = 0;
    __syncthreads();
    for (int j = lo + threadIdx.x; j < hi; j += blockDim.x)
        atomicAdd(&lh[(tmp2[j] >> 8) & 31u], 1);
    __syncthreads();
    if (threadIdx.x < SUBS) {
        int c = lh[threadIdx.x];
        lh[threadIdx.x] = c ? atomicAdd(&bcur[(b0 + threadIdx.x) * CPAD], c) : 0;
    }
    __syncthreads();
    for (int j = lo + threadIdx.x; j < hi; j += blockDim.x) {
        unsigned v = tmp2[j];
        int p = atomicAdd(&lh[(v >> 8) & 31u], 1);
        tmp[p] = ((v >> 13) << 8) | (v & 255u);
    }
}

// ---------------------------------------------------------------------------
// 3c. fallback (small ws): single-pass bin
// ---------------------------------------------------------------------------
__global__ void k_bin1(const int* __restrict__ src, const int* __restrict__ dst,
                       int* __restrict__ bcur, unsigned* __restrict__ tmp,
                       int e, int nba) {
    __shared__ int lh[NBUK];
    for (int b = threadIdx.x; b < NBUK; b += blockDim.x) lh[b] = 0;
    __syncthreads();
    int chunk = (((e + nba - 1) / nba) + 3) & ~3;
    int lo = blockIdx.x * chunk, hi = min(lo + chunk, e);
    for (int j = lo + threadIdx.x; j < hi; j += blockDim.x)
        atomicAdd(&lh[dst[j] >> 8], 1);
    __syncthreads();
    for (int b = threadIdx.x; b < NBUK; b += blockDim.x) {
        int c = lh[b];
        lh[b] = c ? atomicAdd(&bcur[b * CPAD], c) : 0;
    }
    __syncthreads();
    for (int j = lo + threadIdx.x; j < hi; j += blockDim.x) {
        int t = dst[j];
        int p = atomicAdd(&lh[t >> 8], 1);
        tmp[p] = ((unsigned)src[j] << 8) | (unsigned)(t & 255);
    }
}

// ---------------------------------------------------------------------------
// 4. per-bucket: LDS node histogram + block scan -> off[]; LDS-cursor scatter
// ---------------------------------------------------------------------------
__global__ void k_scatter2(const unsigned* __restrict__ tmp, const int* __restrict__ bbase,
                           int* __restrict__ off, int* __restrict__ esrc, int n) {
    __shared__ int ldeg[256];
    __shared__ int lcur[256];
    __shared__ int wtot[4];
    int b = blockIdx.x;
    int t = threadIdx.x;
    int nlo = b << 8;
    int nloc = min(nlo + 256, n) - nlo;
    int lo = bbase[b], hi = bbase[b + 1];

    if (t < 256) ldeg[t] = 0;
    __syncthreads();
    for (int i = lo + t; i < hi; i += blockDim.x)
        atomicAdd(&ldeg[tmp[i] & 255u], 1);
    __syncthreads();

    if (t < 256) {
        int v = ldeg[t];
        int lane = t & 63, wv = t >> 6;
        int s = v;
        for (int o = 1; o < 64; o <<= 1) {
            int u = __shfl_up(s, o);
            if (lane >= o) s += u;
        }
        if (lane == 63) wtot[wv] = s;
        __syncthreads();
        int wb = 0;
        for (int k = 0; k < wv; ++k) wb += wtot[k];
        int pos = lo + wb + s - v;
        if (t < nloc) off[nlo + t] = pos;
        lcur[t] = pos;
    } else {
        __syncthreads();
    }
    __syncthreads();

    for (int i = lo + t; i < hi; i += blockDim.x) {
        unsigned w = tmp[i];
        int p = atomicAdd(&lcur[w & 255u], 1);
        esrc[p] = (int)(w >> 8);
    }
}

// ---------------------------------------------------------------------------
// 5. h1c row i (32-B): dw0..4 = 20 fp8(x@gcn_W), dw5 = fp32 dinv, pad
//    (transposed W in LDS for contiguous reads)
// ---------------------------------------------------------------------------
__global__ void k_xw(const float* __restrict__ x, const float* __restrict__ W,
                     const int* __restrict__ off, uint4* __restrict__ h1c, int n) {
    __shared__ float sWT[D * D];
    for (int t = threadIdx.x; t < D * D; t += blockDim.x)
        sWT[t] = W[(t % D) * D + (t / D)];          // sWT[d*D+k] = W[k*D+d]
    __syncthreads();
    int i = blockIdx.x * blockDim.x + threadIdx.x;
    if (i >= n) return;
    float xi[D];
    const float4* xr = (const float4*)(x + (size_t)i * D);
#pragma unroll
    for (int q = 0; q < D / 4; ++q) {
        float4 v = xr[q];
        xi[4 * q + 0] = v.x; xi[4 * q + 1] = v.y;
        xi[4 * q + 2] = v.z; xi[4 * q + 3] = v.w;
    }
    float h[D];
#pragma unroll
    for (int d = 0; d < D; ++d) {
        const float4* wr = (const float4*)&sWT[d * D];
        float a = 0.f;
#pragma unroll
        for (int kk = 0; kk < D / 4; ++kk) {
            float4 w = wr[kk];
            a += xi[4 * kk + 0] * w.x + xi[4 * kk + 1] * w.y
               + xi[4 * kk + 2] * w.z + xi[4 * kk + 3] * w.w;
        }
        h[d] = a;
    }
    int dg = off[i + 1] - off[i];
    uint4* o = h1c + (size_t)i * 2;
    o[0] = make_uint4(enc4(h[0], h[1], h[2], h[3]), enc4(h[4], h[5], h[6], h[7]),
                      enc4(h[8], h[9], h[10], h[11]), enc4(h[12], h[13], h[14], h[15]));
    o[1] = make_uint4(enc4(h[16], h[17], h[18], h[19]),
                      __float_as_uint(rsqrtf((float)(dg + 1))), 0u, 0u);
}

// ---------------------------------------------------------------------------
// 6. fused GCN gather (8 lanes/node, fp8 rows, software-pipelined) + relu +
//    GAT transform parallelized across the octet (transposed W, LDS staging)
// ---------------------------------------------------------------------------
__global__ void k_gcn_gat(const int* __restrict__ off, const int* __restrict__ esrc,
                          const uint4* __restrict__ h1c, const float* __restrict__ gcn_b,
                          const float* __restrict__ gat_W, const float* __restrict__ att_s,
                          const float* __restrict__ att_d, uint4* __restrict__ h2c, int n) {
    __shared__ float sWT[D * D], sb[D], sas[D], sad[D];
    __shared__ float stage[32][D];
    for (int t = threadIdx.x; t < D * D; t += blockDim.x)
        sWT[t] = gat_W[(t % D) * D + (t / D)];      // sWT[d*D+k] = W[k*D+d]
    if (threadIdx.x < D) {
        sb[threadIdx.x]  = gcn_b[threadIdx.x];
        sas[threadIdx.x] = att_s[threadIdx.x];
        sad[threadIdx.x] = att_d[threadIdx.x];
    }
    __syncthreads();
    int t = threadIdx.x;
    int i = blockIdx.x * (blockDim.x >> 3) + (t >> 3);
    int q = t & 7;
    bool valid = i < n;

    float acc[D];
#pragma unroll
    for (int d = 0; d < D; ++d) acc[d] = 0.f;

    if (valid) {
        const uint4* row = h1c + (size_t)i * 2;
        uint2 r1 = *(const uint2*)(row + 1);
        float di = __uint_as_float(r1.y);
        if (q == 0) {                       // self-loop term
            float v[D];
            dec_row(row[0], r1.x, v);
            float c = di * di;
#pragma unroll
            for (int d = 0; d < D; ++d) acc[d] = c * v[d];
        }
        int s0 = off[i], s1 = off[i + 1];
        int j = s0 + q;
        bool have = j < s1;
        uint4 a_n; uint2 b_n;
        if (have) {
            const uint4* rs = h1c + (size_t)esrc[j] * 2;
            a_n = rs[0];
            b_n = *(const uint2*)(rs + 1);
        }
        while (have) {
            uint4 a = a_n; uint2 b = b_n;
            int jn = j + 8;
            bool hn = jn < s1;
            if (hn) {                        // prefetch next row
                const uint4* rs = h1c + (size_t)esrc[jn] * 2;
                a_n = rs[0];
                b_n = *(const uint2*)(rs + 1);
            }
            float v[D];
            dec_row(a, b.x, v);
            float norm = di * __uint_as_float(b.y);
#pragma unroll
            for (int d = 0; d < D; ++d) acc[d] += norm * v[d];
            j = jn; have = hn;
        }
    }
    // octet all-reduce of acc
#pragma unroll
    for (int d = 0; d < D; ++d) acc[d] += __shfl_xor(acc[d], 1);
#pragma unroll
    for (int d = 0; d < D; ++d) acc[d] += __shfl_xor(acc[d], 2);
#pragma unroll
    for (int d = 0; d < D; ++d) acc[d] += __shfl_xor(acc[d], 4);

    // v = relu(acc + b) in all lanes; each octet lane computes 2-3 channels
    float v[D];
#pragma unroll
    for (int k = 0; k < D; ++k) {
        float tv = acc[k] + sb[k];
        v[k] = tv > 0.f ? tv : 0.f;
    }
    int nb = t >> 3;                         // node slot within block (0..31)
    int d0 = (q < 4) ? 3 * q : 12 + 2 * (q - 4);
    int nd = (q < 4) ? 3 : 2;
    float as_p = 0.f, ad_p = 0.f;
#pragma unroll
    for (int r = 0; r < 3; ++r) {
        if (r < nd) {
            int d = d0 + r;
            const float4* wr = (const float4*)&sWT[d * D];
            float a = 0.f;
#pragma unroll
            for (int kk = 0; kk < D / 4; ++kk) {
                float4 w = wr[kk];
                a += v[4 * kk + 0] * w.x + v[4 * kk + 1] * w.y
                   + v[4 * kk + 2] * w.z + v[4 * kk + 3] * w.w;
            }
            stage[nb][d] = a;
            as_p += a * sas[d];
            ad_p += a * sad[d];
        }
    }
    as_p += __shfl_xor(as_p, 1); as_p += __shfl_xor(as_p, 2); as_p += __shfl_xor(as_p, 4);
    ad_p += __shfl_xor(ad_p, 1); ad_p += __shfl_xor(ad_p, 2); ad_p += __shfl_xor(ad_p, 4);
    if (valid && q == 0) {                   // lane 0: pack + store
        const float* hs = stage[nb];
        uint4* o = h2c + (size_t)i * 2;
        o[0] = make_uint4(enc4(hs[0], hs[1], hs[2], hs[3]),
                          enc4(hs[4], hs[5], hs[6], hs[7]),
                          enc4(hs[8], hs[9], hs[10], hs[11]),
                          enc4(hs[12], hs[13], hs[14], hs[15]));
        o[1] = make_uint4(enc4(hs[16], hs[17], hs[18], hs[19]),
                          __float_as_uint(as_p), __float_as_uint(ad_p), 0u);
    }
}

// ---------------------------------------------------------------------------
// 7. GAT online-softmax aggregate, 8 lanes/node, fp8 rows, software-pipelined
// ---------------------------------------------------------------------------
__global__ void k_gat_agg(const int* __restrict__ off, const int* __restrict__ esrc,
                          const uint4* __restrict__ h2c, const float* __restrict__ gat_b,
                          float* __restrict__ partials, int PB, int n) {
    __shared__ float sb[D];
    __shared__ float swave[4][D];
    if (threadIdx.x < D) sb[threadIdx.x] = gat_b[threadIdx.x];
    __syncthreads();
    int t = threadIdx.x;
    int i = blockIdx.x * (blockDim.x >> 3) + (t >> 3);
    int o = t & 7;
    bool valid = i < n;

    float m = -1e30f, den = 0.f;
    float acc[D];
#pragma unroll
    for (int d = 0; d < D; ++d) acc[d] = 0.f;

    if (valid) {
        const uint4* row = h2c + (size_t)i * 2;
        uint4 r1 = row[1];
        float ad_i = __uint_as_float(r1.z);
        if (o == 0) {                      // self edge seeds the online softmax
            m = leaky(__uint_as_float(r1.y) + ad_i);
            den = 1.f;
            float v[D];
            dec_row(row[0], r1.x, v);
#pragma unroll
            for (int d = 0; d < D; ++d) acc[d] = v[d];
        }
        int s0 = off[i], s1 = off[i + 1];
        int j = s0 + o;
        bool have = j < s1;
        uint4 a_n; uint2 b_n;
        if (have) {
            const uint4* rs = h2c + (size_t)esrc[j] * 2;
            a_n = rs[0];
            b_n = *(const uint2*)(rs + 1);   // {ch16-19, a_src}
        }
        while (have) {
            uint4 a = a_n; uint2 b = b_n;
            int jn = j + 8;
            bool hn = jn < s1;
            if (hn) {                        // prefetch next row
                const uint4* rs = h2c + (size_t)esrc[jn] * 2;
                a_n = rs[0];
                b_n = *(const uint2*)(rs + 1);
            }
            float v[D];
            dec_row(a, b.x, v);
            float eg = leaky(__uint_as_float(b.y) + ad_i);
            float nm = fmaxf(m, eg);
            float cs = __expf(m - nm), w = __expf(eg - nm);
            den = den * cs + w;
#pragma unroll
            for (int d = 0; d < D; ++d) acc[d] = acc[d] * cs + w * v[d];
            m = nm;
            j = jn; have = hn;
        }
    }
    // octet merge of (m, den, acc)
#pragma unroll
    for (int mask = 1; mask < 8; mask <<= 1) {
        float om = __shfl_xor(m, mask);
        float oden = __shfl_xor(den, mask);
        float nm = fmaxf(m, om);
        float c1 = __expf(m - nm), c2 = __expf(om - nm);
        den = den * c1 + oden * c2;
#pragma unroll
        for (int d = 0; d < D; ++d) {
            float oa = __shfl_xor(acc[d], mask);
            acc[d] = acc[d] * c1 + oa * c2;
        }
        m = nm;
    }
    float inv = den > 0.f ? 1.0f / den : 0.f;
#pragma unroll
    for (int d = 0; d < D; ++d) {
        float vv = acc[d] * inv + sb[d];
        vv = vv > 0.f ? vv : 0.f;
        if (!valid || o != 0) vv = 0.f;
        acc[d] = vv;
    }
    int wv = t >> 6, ln = t & 63;
#pragma unroll
    for (int d = 0; d < D; ++d) {
        float vv = acc[d];
        for (int s2 = 32; s2; s2 >>= 1) vv += __shfl_down(vv, s2);
        if (ln == 0) swave[wv][d] = vv;
    }
    __syncthreads();
    if (t < D) {
        float s = swave[0][t] + swave[1][t] + swave[2][t] + swave[3][t];
        partials[(size_t)t * PB + blockIdx.x] = s;
    }
}

// ---------------------------------------------------------------------------
// 8. final readout reduce: one block per channel, no atomics
// ---------------------------------------------------------------------------
__global__ void k_reduce(const float* __restrict__ partials, int PB, int nblk,
                         float* __restrict__ g) {
    __shared__ float swave[4];
    int d = blockIdx.x;
    int t = threadIdx.x;
    const float* p = partials + (size_t)d * PB;
    float s = 0.f;
    for (int i = t; i < nblk; i += blockDim.x) s += p[i];
    for (int s2 = 32; s2; s2 >>= 1) s += __shfl_down(s, s2);
    if ((t & 63) == 0) swave[t >> 6] = s;
    __syncthreads();
    if (t == 0) g[d] = swave[0] + swave[1] + swave[2] + swave[3];
}

// ---------------------------------------------------------------------------
// 9. dueling head
// ---------------------------------------------------------------------------
__global__ void k_head(const float* __restrict__ g,
                       const float* __restrict__ aW1, const float* __restrict__ ab1,
                       const float* __restrict__ aW2, const float* __restrict__ ab2,
                       const float* __restrict__ vW1, const float* __restrict__ vb1,
                       const float* __restrict__ vW2, const float* __restrict__ vb2,
                       float* __restrict__ out) {
    __shared__ float sg[D], t1[D], t2[D], A[ACT], V, meanA;
    int t = threadIdx.x;
    if (t < D) sg[t] = g[t];
    __syncthreads();
    if (t < D) {
        float a = ab1[t], v = vb1[t];
        for (int k = 0; k < D; ++k) {
            a += sg[k] * aW1[k * D + t];
            v += sg[k] * vW1[k * D + t];
        }
        t1[t] = a > 0.f ? a : 0.f;
        t2[t] = v > 0.f ? v : 0.f;
    }
    __syncthreads();
    if (t < ACT) {
        float a = ab2[t];
        for (int d = 0; d < D; ++d) a += t1[d] * aW2[d * ACT + t];
        A[t] = a;
    }
    if (t == D) {
        float v = vb2[0];
        for (int d = 0; d < D; ++d) v += t2[d] * vW2[d];
        V = v;
    }
    __syncthreads();
    if (t == 0) {
        float s = 0.f;
        for (int j = 0; j < ACT; ++j) s += A[j];
        meanA = s / ACT;
    }
    __syncthreads();
    if (t < ACT) out[t] = V + A[t] - meanA;
}

extern "C" void kernel_launch(void* const* d_in, const int* in_sizes, int n_in,
                              void* d_out, int out_size, void* d_ws, size_t ws_size,
                              hipStream_t stream) {
    const float* x      = (const float*)d_in[0];
    const int*   ei     = (const int*)d_in[1];
    // d_in[2] edge_attr: unused by the reference
    const float* gcn_W  = (const float*)d_in[3];
    const float* gcn_b  = (const float*)d_in[4];
    const float* gat_W  = (const float*)d_in[5];
    const float* att_s  = (const float*)d_in[6];
    const float* att_d  = (const float*)d_in[7];
    const float* gat_b  = (const float*)d_in[8];
    const float* aW1    = (const float*)d_in[9];
    const float* ab1    = (const float*)d_in[10];
    const float* aW2    = (const float*)d_in[11];
    const float* ab2    = (const float*)d_in[12];
    const float* vW1    = (const float*)d_in[13];
    const float* vb1    = (const float*)d_in[14];
    const float* vW2    = (const float*)d_in[15];
    const float* vb2    = (const float*)d_in[16];

    const int n = in_sizes[0] / D;       // 100000
    const int e = in_sizes[1] / 2;       // 3200000
    const int* src = ei;
    const int* dst = ei + e;

    const int B = 256;
    const int nb_n = (n + B - 1) / B;
    const int nb_o = (n + 31) / 32;                 // 8 lanes/node
    const int PB   = (nb_o + 63) & ~63;
    const int nbuk_used = (n + 255) >> 8;           // 391

    // workspace layout: region A = max(E dwords, h1c+h2c) — tmp2 dead before k_xw
    char* p = (char*)d_ws;
    size_t regionA = (size_t)e * 4;
    size_t hsz = (size_t)n * 64;                    // h1c(32B) + h2c(32B) per node
    if (hsz > regionA) regionA = hsz;
    uint4* h1c      = (uint4*)p;                    // n*2 uint4
    uint4* h2c      = h1c + (size_t)n * 2;          // n*2 uint4
    unsigned* tmp2  = (unsigned*)p;                 // E dwords (aliases h1c/h2c)
    p += regionA;
    float* g        = (float*)p;        p += 32 * sizeof(float);
    float* partials = (float*)p;        p += (size_t)D * PB * sizeof(float);
    int*   off      = (int*)p;          p += (size_t)(n + 1) * sizeof(int);
    int*   bkt      = (int*)p;          p += (size_t)NBUK * CPAD * sizeof(int);
    int*   bbase    = (int*)p;          p += (size_t)(NBUK + 1) * sizeof(int);
    int*   bcur     = (int*)p;          p += (size_t)NBUK * CPAD * sizeof(int);
    int*   scur     = (int*)p;          p += (size_t)16 * CPAD * sizeof(int);
    int*   esrc     = (int*)p;          p += (size_t)e * sizeof(int);
    unsigned* tmp   = (unsigned*)p;     p += (size_t)e * sizeof(unsigned);
    size_t need2 = (size_t)(p - (char*)d_ws);
    bool two_pass = ws_size >= need2;

    hipMemsetAsync(bkt, 0, NBUK * CPAD * sizeof(int), stream);

    k_bhist<<<1024, B, 0, stream>>>(dst, bkt, e);
    k_bscan<<<1, 256, 0, stream>>>(bkt, bbase, bcur, scur, &off[n], e);
    if (two_pass) {
        kA_bin<<<256, B, 0, stream>>>(src, dst, scur, tmp2, e, 256);
        kB_bin<<<NSUP * 32, B, 0, stream>>>(tmp2, bbase, bcur, tmp);
    } else {
        tmp = tmp2;   // fallback: single-pass bin into region A
        k_bin1<<<1024, B, 0, stream>>>(src, dst, bcur, tmp, e, 1024);
    }
    k_scatter2<<<nbuk_used, 512, 0, stream>>>(tmp, bbase, off, esrc, n);
    k_xw<<<nb_n, B, 0, stream>>>(x, gcn_W, off, h1c, n);
    k_gcn_gat<<<nb_o, B, 0, stream>>>(off, esrc, h1c, gcn_b, gat_W,
                                      att_s, att_d, h2c, n);
    k_gat_agg<<<nb_o, B, 0, stream>>>(off, esrc, h2c, gat_b, partials, PB, n);
    k_reduce<<<D, B, 0, stream>>>(partials, PB, nb_o, g);
    k_head<<<1, 64, 0, stream>>>(g, aW1, ab1, aW2, ab2, vW1, vb1, vW2, vb2,
                                 (float*)d_out);
}